// Round 1
// baseline (217.811 us; speedup 1.0000x reference)
//
#include <hip/hip_runtime.h>
#include <hip/hip_bf16.h>
#include <math.h>

// Problem constants
#define BTOT 32768

// Scratch in device globals (graph-capture safe, no ws_size assumptions).
__device__ float g_x[BTOT * 128];        // 16.8 MB intermediate state
__device__ float g_M[2 * 8 * 16 * 64];   // folded AT^T @ pw_w1, per (l,p): 16x64
__device__ float g_b1p[2 * 8 * 64];      // pw_b1 + colsum(pw_w1)

__device__ __forceinline__ float gelu_f(float v) {
    return 0.5f * v * (1.0f + erff(v * 0.70710678118654752f));
}

// ---------------------------------------------------------------------------
// k_pre: per (l,p) block. Phase 1: slerp anchor matrices AT[48][16] (weights
// only). Phase 2: M[d][h] = sum_j AT[j][d]*w1[j][h]; b1p[h] = b1[h]+sum_j w1[j][h].
// ---------------------------------------------------------------------------
__global__ __launch_bounds__(64) void k_pre(const float* __restrict__ home,
                                            const float* __restrict__ anchors,
                                            const float* __restrict__ pw_w1,
                                            const float* __restrict__ pw_b1) {
    __shared__ float s_AT[48 * 16];
    const int lp = blockIdx.x;   // 0..15  (l*8+p)
    const int tid = threadIdx.x; // 0..63
    if (tid < 48) {
        const int t = tid >> 4, a = tid & 15;
        const float* hp = home + (lp * 16 + a) * 16;
        const float* cp = anchors + (lp * 16 + a) * 16;
        float h[16], c[16], nh = 0.f, nc = 0.f;
#pragma unroll
        for (int i = 0; i < 16; ++i) {
            h[i] = hp[i]; nh = fmaf(h[i], h[i], nh);
            c[i] = cp[i]; nc = fmaf(c[i], c[i], nc);
        }
        const float ih = 1.f / fmaxf(sqrtf(nh), 1e-12f);
        const float ic = 1.f / fmaxf(sqrtf(nc), 1e-12f);
        float cw = 0.f;
#pragma unroll
        for (int i = 0; i < 16; ++i) { h[i] *= ih; c[i] *= ic; cw = fmaf(h[i], c[i], cw); }
        cw = fminf(fmaxf(cw, -1.f + 1e-7f), 1.f - 1e-7f);
        const float om = acosf(cw);
        const float so = fmaxf(sinf(om), 1e-7f);
        const float tt = (float)t * (1.f / 3.f);
        const float s1 = sinf((1.f - tt) * om), s2 = sinf(tt * om);
        float v[16], nv = 0.f;
#pragma unroll
        for (int i = 0; i < 16; ++i) { v[i] = (s1 * h[i] + s2 * c[i]) / so; nv = fmaf(v[i], v[i], nv); }
        const float iv = 1.f / fmaxf(sqrtf(nv), 1e-12f);
#pragma unroll
        for (int i = 0; i < 16; ++i) s_AT[tid * 16 + i] = v[i] * iv;
    }
    __syncthreads();
    const int h = tid;
    const float* w1 = pw_w1 + lp * 48 * 64;
    float b = pw_b1[lp * 64 + h];
    float m[16];
#pragma unroll
    for (int d = 0; d < 16; ++d) m[d] = 0.f;
    for (int j = 0; j < 48; ++j) {
        const float w = w1[j * 64 + h];
        b += w;
#pragma unroll
        for (int d = 0; d < 16; ++d) m[d] = fmaf(s_AT[j * 16 + d], w, m[d]);
    }
    g_b1p[lp * 64 + h] = b;
#pragma unroll
    for (int d = 0; d < 16; ++d) g_M[(lp * 16 + d) * 64 + h] = m[d];
}

// ---------------------------------------------------------------------------
// k_front: x[64rows][128] = [emb@emb_w+b | tri@tri_w+b | rm] @ ctx_w + ctx_b
// 256 threads, 64 rows/WG. LDS-tiled f32 GEMMs with 4x4 register micro-tiles.
// ---------------------------------------------------------------------------
__global__ __launch_bounds__(256) void k_front(const float* __restrict__ emb,
                                               const float* __restrict__ tri,
                                               const float* __restrict__ rm,
                                               const float* __restrict__ emb_w,
                                               const float* __restrict__ emb_b,
                                               const float* __restrict__ tri_w,
                                               const float* __restrict__ tri_b,
                                               const float* __restrict__ ctx_w,
                                               const float* __restrict__ ctx_b) {
    // A tile at [r*136 + 0..67], W tile at [r*136 + 68..]; reused as ctx_w tile [k*132 + c]
    __shared__ __align__(16) float s_ab[64 * 136];
    __shared__ __align__(16) float s_ctx[64 * 100];
    const int tid = threadIdx.x;
    const int row0 = blockIdx.x * 64;
    const int pr = tid >> 4, qc = tid & 15;
    const int rb = pr * 4;

    // ---- C1 = emb @ emb_w  (64x768 @ 768x64)
    {
        const int cb = qc * 4;
        float acc[4][4];
#pragma unroll
        for (int i = 0; i < 4; ++i)
#pragma unroll
            for (int j = 0; j < 4; ++j) acc[i][j] = 0.f;
        for (int kc = 0; kc < 12; ++kc) {
#pragma unroll
            for (int i = 0; i < 4; ++i) {
                const int q = tid + i * 256;
                const int r = q >> 4, c4 = q & 15;
                *(float4*)&s_ab[r * 136 + c4 * 4] =
                    *(const float4*)&emb[(size_t)(row0 + r) * 768 + kc * 64 + c4 * 4];
                *(float4*)&s_ab[r * 136 + 68 + c4 * 4] =
                    *(const float4*)&emb_w[(kc * 64 + r) * 64 + c4 * 4];
            }
            __syncthreads();
#pragma unroll 4
            for (int k4 = 0; k4 < 16; ++k4) {
                float a[4][4];
#pragma unroll
                for (int i = 0; i < 4; ++i)
                    *(float4*)a[i] = *(const float4*)&s_ab[(rb + i) * 136 + k4 * 4];
#pragma unroll
                for (int kk = 0; kk < 4; ++kk) {
                    float w[4];
                    *(float4*)w = *(const float4*)&s_ab[(k4 * 4 + kk) * 136 + 68 + cb];
#pragma unroll
                    for (int i = 0; i < 4; ++i)
#pragma unroll
                        for (int j = 0; j < 4; ++j) acc[i][j] = fmaf(a[i][kk], w[j], acc[i][j]);
                }
            }
            __syncthreads();
        }
#pragma unroll
        for (int i = 0; i < 4; ++i)
#pragma unroll
            for (int j = 0; j < 4; ++j)
                s_ctx[(rb + i) * 100 + cb + j] = acc[i][j] + emb_b[cb + j];
    }

    // ---- C2 = tri @ tri_w (64x1024 @ 1024x32)
    {
        const int cb = qc * 2;
        float acc[4][2];
#pragma unroll
        for (int i = 0; i < 4; ++i) { acc[i][0] = 0.f; acc[i][1] = 0.f; }
        for (int kc = 0; kc < 16; ++kc) {
#pragma unroll
            for (int i = 0; i < 4; ++i) {
                const int q = tid + i * 256;
                const int r = q >> 4, c4 = q & 15;
                *(float4*)&s_ab[r * 136 + c4 * 4] =
                    *(const float4*)&tri[(size_t)(row0 + r) * 1024 + kc * 64 + c4 * 4];
            }
#pragma unroll
            for (int i = 0; i < 2; ++i) {
                const int q = tid + i * 256;
                const int r = q >> 3, c4 = q & 7;
                *(float4*)&s_ab[r * 136 + 68 + c4 * 4] =
                    *(const float4*)&tri_w[(kc * 64 + r) * 32 + c4 * 4];
            }
            __syncthreads();
#pragma unroll 4
            for (int k4 = 0; k4 < 16; ++k4) {
                float a[4][4];
#pragma unroll
                for (int i = 0; i < 4; ++i)
                    *(float4*)a[i] = *(const float4*)&s_ab[(rb + i) * 136 + k4 * 4];
#pragma unroll
                for (int kk = 0; kk < 4; ++kk) {
                    const float w0 = s_ab[(k4 * 4 + kk) * 136 + 68 + cb];
                    const float w1 = s_ab[(k4 * 4 + kk) * 136 + 68 + cb + 1];
#pragma unroll
                    for (int i = 0; i < 4; ++i) {
                        acc[i][0] = fmaf(a[i][kk], w0, acc[i][0]);
                        acc[i][1] = fmaf(a[i][kk], w1, acc[i][1]);
                    }
                }
            }
            __syncthreads();
        }
#pragma unroll
        for (int i = 0; i < 4; ++i) {
            s_ctx[(rb + i) * 100 + 64 + cb] = acc[i][0] + tri_b[cb];
            s_ctx[(rb + i) * 100 + 64 + cb + 1] = acc[i][1] + tri_b[cb + 1];
        }
    }
    if (tid < 64) s_ctx[tid * 100 + 96] = rm[row0 + tid];
    __syncthreads();

    // ---- X = ctx @ ctx_w + ctx_b  (64x97 @ 97x128)
    {
        const int c8 = qc * 8;
        float acc[4][8];
#pragma unroll
        for (int i = 0; i < 4; ++i)
#pragma unroll
            for (int j = 0; j < 8; ++j) acc[i][j] = 0.f;
        // chunk 1: k = 0..63
        for (int q = tid; q < 2048; q += 256) {
            const int r = q >> 5, c4 = q & 31;
            *(float4*)&s_ab[r * 132 + c4 * 4] = *(const float4*)&ctx_w[r * 128 + c4 * 4];
        }
        __syncthreads();
        for (int k = 0; k < 64; ++k) {
            float w[8];
            *(float4*)&w[0] = *(const float4*)&s_ab[k * 132 + c8];
            *(float4*)&w[4] = *(const float4*)&s_ab[k * 132 + c8 + 4];
#pragma unroll
            for (int i = 0; i < 4; ++i) {
                const float a = s_ctx[(rb + i) * 100 + k];
#pragma unroll
                for (int j = 0; j < 8; ++j) acc[i][j] = fmaf(a, w[j], acc[i][j]);
            }
        }
        __syncthreads();
        // chunk 2: k = 64..96 (33 rows)
        for (int q = tid; q < 1056; q += 256) {
            const int r = q >> 5, c4 = q & 31;
            *(float4*)&s_ab[r * 132 + c4 * 4] = *(const float4*)&ctx_w[(64 + r) * 128 + c4 * 4];
        }
        __syncthreads();
        for (int k = 0; k < 33; ++k) {
            float w[8];
            *(float4*)&w[0] = *(const float4*)&s_ab[k * 132 + c8];
            *(float4*)&w[4] = *(const float4*)&s_ab[k * 132 + c8 + 4];
#pragma unroll
            for (int i = 0; i < 4; ++i) {
                const float a = s_ctx[(rb + i) * 100 + 64 + k];
#pragma unroll
                for (int j = 0; j < 8; ++j) acc[i][j] = fmaf(a, w[j], acc[i][j]);
            }
        }
#pragma unroll
        for (int i = 0; i < 4; ++i) {
            float o[8];
#pragma unroll
            for (int j = 0; j < 8; ++j) o[j] = acc[i][j] + ctx_b[c8 + j];
            *(float4*)&g_x[(size_t)(row0 + rb + i) * 128 + c8] = *(float4*)&o[0];
            *(float4*)&g_x[(size_t)(row0 + rb + i) * 128 + c8 + 4] = *(float4*)&o[4];
        }
    }
}

// ---------------------------------------------------------------------------
// k_relay: 2 relay layers + head + output writes. 32 rows/WG, thread=(row,patch),
// x kept in registers across layers; LN row-reduction via shfl over 8 lanes.
// M/w2 staged in LDS with p-stride 1028 (=> p spreads banks, conflict-free).
// ---------------------------------------------------------------------------
__global__ __launch_bounds__(256) void k_relay(
    const float* __restrict__ pw_w2, const float* __restrict__ pw_b2,
    const float* __restrict__ pwn_g, const float* __restrict__ pwn_b,
    const float* __restrict__ gates, const float* __restrict__ norm_g,
    const float* __restrict__ norm_b, const float* __restrict__ head_w1,
    const float* __restrict__ head_b1, const float* __restrict__ head_w2,
    const float* __restrict__ head_b2, const float* __restrict__ stats_bias,
    float* __restrict__ out) {
    __shared__ __align__(16) float s_M[8 * 1028];
    __shared__ __align__(16) float s_w2[8 * 1028];
    __shared__ __align__(16) float s_b1p[8 * 68];
    __shared__ __align__(16) float s_hw1[8 * 132];
    __shared__ float s_hb1[64], s_hw2[64], s_hcb[8];
    __shared__ float s_mc[32 * 8];
    const int tid = threadIdx.x;
    const int r = tid >> 3, p = tid & 7;
    const int row = blockIdx.x * 32 + r;

    {   // stage head weights (256 float4 == 1024 floats exactly)
        const int e = tid * 4, pp = e >> 7, rem = e & 127;
        *(float4*)&s_hw1[pp * 132 + rem] = *(const float4*)&head_w1[e];
    }
    if (tid < 64) { s_hb1[tid] = head_b1[tid]; s_hw2[tid] = head_w2[tid]; }
    if (tid < 8) s_hcb[tid] = head_b2[tid] + stats_bias[tid];

    float x[16];
    {
        const float* xp = g_x + (size_t)row * 128 + p * 16;
#pragma unroll
        for (int i = 0; i < 4; ++i) *(float4*)&x[i * 4] = *(const float4*)&xp[i * 4];
    }

    for (int l = 0; l < 2; ++l) {
        if (l) __syncthreads();
        for (int q = tid; q < 2048; q += 256) {
            const int e = q * 4, pp = e >> 10, rem = e & 1023;
            *(float4*)&s_M[pp * 1028 + rem] = *(const float4*)&g_M[l * 8192 + e];
            *(float4*)&s_w2[pp * 1028 + rem] = *(const float4*)&pw_w2[l * 8192 + e];
        }
        if (tid < 128) {
            const int e = tid * 4, pp = e >> 6, rem = e & 63;
            *(float4*)&s_b1p[pp * 68 + rem] = *(const float4*)&g_b1p[l * 512 + e];
        }
        __syncthreads();

        // LayerNorm over the 128-dim row (8 lanes of same row cooperate)
        float sum = 0.f, sq = 0.f;
#pragma unroll
        for (int i = 0; i < 16; ++i) { sum += x[i]; sq = fmaf(x[i], x[i], sq); }
#pragma unroll
        for (int m = 1; m < 8; m <<= 1) {
            sum += __shfl_xor(sum, m, 64);
            sq += __shfl_xor(sq, m, 64);
        }
        const float mu = sum * (1.f / 128.f);
        const float rstd = rsqrtf(fmaxf(sq * (1.f / 128.f) - mu * mu, 0.f) + 1e-5f);
        float patch[16], n2 = 0.f;
#pragma unroll
        for (int i = 0; i < 16; ++i) {
            const float v = (x[i] - mu) * rstd * norm_g[l * 128 + p * 16 + i] + norm_b[l * 128 + p * 16 + i];
            patch[i] = v;
            n2 = fmaf(v, v, n2);
        }
        const float inv = 1.f / fmaxf(sqrtf(n2), 1e-12f);
        float pn[16];
#pragma unroll
        for (int i = 0; i < 16; ++i) pn[i] = -patch[i] * inv;  // negated for fnma form
        float pw[16];
#pragma unroll
        for (int i = 0; i < 16; ++i) pw[i] = pw_b2[(l * 8 + p) * 16 + i];
        const float* Mp = &s_M[p * 1028];
        const float* W2p = &s_w2[p * 1028];
        const float* Bp = &s_b1p[p * 68];
        for (int h4 = 0; h4 < 16; ++h4) {
            float a[4];
            *(float4*)a = *(const float4*)&Bp[h4 * 4];
#pragma unroll
            for (int d = 0; d < 16; ++d) {
                float m[4];
                *(float4*)m = *(const float4*)&Mp[d * 64 + h4 * 4];
#pragma unroll
                for (int j = 0; j < 4; ++j) a[j] = fmaf(pn[d], m[j], a[j]);
            }
#pragma unroll
            for (int j = 0; j < 4; ++j) {
                const float g = gelu_f(a[j]);
                float w[16];
#pragma unroll
                for (int u = 0; u < 4; ++u)
                    *(float4*)&w[u * 4] = *(const float4*)&W2p[(h4 * 4 + j) * 16 + u * 4];
#pragma unroll
                for (int u = 0; u < 16; ++u) pw[u] = fmaf(g, w[u], pw[u]);
            }
        }
        // LN16 on pw, gate, residual combine
        float s2 = 0.f, q2 = 0.f;
#pragma unroll
        for (int i = 0; i < 16; ++i) { s2 += pw[i]; q2 = fmaf(pw[i], pw[i], q2); }
        const float mu2 = s2 * (1.f / 16.f);
        const float rs2 = rsqrtf(fmaxf(q2 * (1.f / 16.f) - mu2 * mu2, 0.f) + 1e-5f);
        const float gate = 1.f / (1.f + expf(-gates[l * 8 + p]));
#pragma unroll
        for (int i = 0; i < 16; ++i) {
            const float v = (pw[i] - mu2) * rs2 * pwn_g[l * 16 + i] + pwn_b[l * 16 + i];
            x[i] = x[i] + gate * v + (1.f - gate) * patch[i];
        }
    }

    // head: per (row, patch) fully thread-local
    float accm = s_hcb[p];
#pragma unroll
    for (int j = 0; j < 8; ++j) {
        float a = s_hb1[p * 8 + j];
#pragma unroll
        for (int d = 0; d < 16; ++d) a = fmaf(x[d], s_hw1[p * 132 + d * 8 + j], a);
        accm = fmaf(gelu_f(a), s_hw2[p * 8 + j], accm);
    }
    const float mc = 0.1f + 4.9f / (1.f + expf(-accm));
    s_mc[r * 8 + p] = mc;
    out[(size_t)33554432 + (size_t)row * 8 + p] = mc;
    __syncthreads();

    // mag = repeat(mc, 128): cooperative fully-coalesced float4 writes
    const size_t base = (size_t)blockIdx.x * 32 * 1024;
#pragma unroll
    for (int it = 0; it < 32; ++it) {
        const int idx = it * 256 + tid;
        const int rr = idx >> 8, c4 = idx & 255;
        const float v = s_mc[rr * 8 + (c4 >> 5)];
        const float4 vv = make_float4(v, v, v, v);
        *(float4*)&out[base + rr * 1024 + c4 * 4] = vv;
    }
}

// ---------------------------------------------------------------------------
extern "C" void kernel_launch(void* const* d_in, const int* in_sizes, int n_in,
                              void* d_out, int out_size, void* d_ws, size_t ws_size,
                              hipStream_t stream) {
    (void)in_sizes; (void)n_in; (void)d_ws; (void)ws_size; (void)out_size;
    const float* emb = (const float*)d_in[0];
    const float* tria = (const float*)d_in[1];
    const float* rm = (const float*)d_in[2];
    const float* emb_w = (const float*)d_in[3];
    const float* emb_b = (const float*)d_in[4];
    const float* tri_w = (const float*)d_in[5];
    const float* tri_b = (const float*)d_in[6];
    const float* ctx_w = (const float*)d_in[7];
    const float* ctx_b = (const float*)d_in[8];
    const float* home = (const float*)d_in[9];
    const float* anch = (const float*)d_in[10];
    const float* pw_w1 = (const float*)d_in[11];
    const float* pw_b1 = (const float*)d_in[12];
    const float* pw_w2 = (const float*)d_in[13];
    const float* pw_b2 = (const float*)d_in[14];
    const float* pwn_g = (const float*)d_in[15];
    const float* pwn_b = (const float*)d_in[16];
    const float* gates = (const float*)d_in[17];
    const float* norm_g = (const float*)d_in[18];
    const float* norm_b = (const float*)d_in[19];
    const float* hw1 = (const float*)d_in[20];
    const float* hb1 = (const float*)d_in[21];
    const float* hw2 = (const float*)d_in[22];
    const float* hb2 = (const float*)d_in[23];
    const float* sb = (const float*)d_in[24];
    float* out = (float*)d_out;

    k_pre<<<16, 64, 0, stream>>>(home, anch, pw_w1, pw_b1);
    k_front<<<512, 256, 0, stream>>>(emb, tria, rm, emb_w, emb_b, tri_w, tri_b, ctx_w, ctx_b);
    k_relay<<<1024, 256, 0, stream>>>(pw_w2, pw_b2, pwn_g, pwn_b, gates, norm_g, norm_b,
                                      hw1, hb1, hw2, hb2, sb, out);
}

// Round 2
// 214.782 us; speedup vs baseline: 1.0141x; 1.0141x over previous
//
#include <hip/hip_runtime.h>
#include <hip/hip_bf16.h>
#include <math.h>

#define BTOT 32768

typedef float f32x4 __attribute__((ext_vector_type(4)));
typedef __bf16 v8bf __attribute__((ext_vector_type(8)));

// Scratch in device globals (graph-capture safe).
__device__ float g_x[BTOT * 128];                       // 16.8 MB intermediate
__device__ float g_M[2 * 8 * 16 * 64];                  // folded AT^T @ pw_w1
__device__ float g_b1p[2 * 8 * 64];                     // pw_b1 + colsum(pw_w1)
__device__ __align__(16) unsigned short g_wf[1792 * 128]; // [E;T] bf16, B-fragment-swizzled
__device__ float g_beff[128];                           // ctx_b + emb_b@Wc1 + tri_b@Wc2
__device__ float g_wr[128];                             // ctx_w row 96 (rm column)

__device__ __forceinline__ float gelu_f(float v) {
    return 0.5f * v * (1.0f + erff(v * 0.70710678118654752f));
}

__device__ __forceinline__ unsigned short f2bf_rne(float x) {
    unsigned u = __float_as_uint(x);
    u += 0x7fffu + ((u >> 16) & 1u);
    return (unsigned short)(u >> 16);
}

// ---------------------------------------------------------------------------
// k_pre: per (l,p): slerp anchors -> fold AT^T @ pw_w1 into g_M, g_b1p.
// ---------------------------------------------------------------------------
__global__ __launch_bounds__(64) void k_pre(const float* __restrict__ home,
                                            const float* __restrict__ anchors,
                                            const float* __restrict__ pw_w1,
                                            const float* __restrict__ pw_b1) {
    __shared__ float s_AT[48 * 16];
    const int lp = blockIdx.x;   // 0..15  (l*8+p)
    const int tid = threadIdx.x; // 0..63
    if (tid < 48) {
        const int t = tid >> 4, a = tid & 15;
        const float* hp = home + (lp * 16 + a) * 16;
        const float* cp = anchors + (lp * 16 + a) * 16;
        float h[16], c[16], nh = 0.f, nc = 0.f;
#pragma unroll
        for (int i = 0; i < 16; ++i) {
            h[i] = hp[i]; nh = fmaf(h[i], h[i], nh);
            c[i] = cp[i]; nc = fmaf(c[i], c[i], nc);
        }
        const float ih = 1.f / fmaxf(sqrtf(nh), 1e-12f);
        const float ic = 1.f / fmaxf(sqrtf(nc), 1e-12f);
        float cw = 0.f;
#pragma unroll
        for (int i = 0; i < 16; ++i) { h[i] *= ih; c[i] *= ic; cw = fmaf(h[i], c[i], cw); }
        cw = fminf(fmaxf(cw, -1.f + 1e-7f), 1.f - 1e-7f);
        const float om = acosf(cw);
        const float so = fmaxf(sinf(om), 1e-7f);
        const float tt = (float)t * (1.f / 3.f);
        const float s1 = sinf((1.f - tt) * om), s2 = sinf(tt * om);
        float v[16], nv = 0.f;
#pragma unroll
        for (int i = 0; i < 16; ++i) { v[i] = (s1 * h[i] + s2 * c[i]) / so; nv = fmaf(v[i], v[i], nv); }
        const float iv = 1.f / fmaxf(sqrtf(nv), 1e-12f);
#pragma unroll
        for (int i = 0; i < 16; ++i) s_AT[tid * 16 + i] = v[i] * iv;
    }
    __syncthreads();
    const int h = tid;
    const float* w1 = pw_w1 + lp * 48 * 64;
    float b = pw_b1[lp * 64 + h];
    float m[16];
#pragma unroll
    for (int d = 0; d < 16; ++d) m[d] = 0.f;
    for (int j = 0; j < 48; ++j) {
        const float w = w1[j * 64 + h];
        b += w;
#pragma unroll
        for (int d = 0; d < 16; ++d) m[d] = fmaf(s_AT[j * 16 + d], w, m[d]);
    }
    g_b1p[lp * 64 + h] = b;
#pragma unroll
    for (int d = 0; d < 16; ++d) g_M[(lp * 16 + d) * 64 + h] = m[d];
}

// ---------------------------------------------------------------------------
// k_fold: W = [emb_w@Wc1 ; tri_w@Wc2] (1792x128) -> bf16, swizzled into MFMA
// B-fragment-linear order: g_wf[((kt*8+nt)*64 + lane)*8 + j] =
//   W[kt*32 + (lane>>4)*8 + j][nt*16 + (lane&15)].
// Block 56 also computes b_eff and wr.
// ---------------------------------------------------------------------------
__global__ __launch_bounds__(256) void k_fold(const float* __restrict__ emb_w,
                                              const float* __restrict__ tri_w,
                                              const float* __restrict__ ctx_w,
                                              const float* __restrict__ ctx_b,
                                              const float* __restrict__ emb_b,
                                              const float* __restrict__ tri_b) {
    if (blockIdx.x == 56) {
        const int n = threadIdx.x;
        if (n < 128) {
            float b = ctx_b[n];
            for (int c = 0; c < 64; ++c) b = fmaf(emb_b[c], ctx_w[c * 128 + n], b);
            for (int c = 0; c < 32; ++c) b = fmaf(tri_b[c], ctx_w[(64 + c) * 128 + n], b);
            g_beff[n] = b;
            g_wr[n] = ctx_w[96 * 128 + n];
        }
        return;
    }
    __shared__ float sctx[97 * 128];
    for (int q = threadIdx.x; q < 3104; q += 256)
        *(float4*)&sctx[q * 4] = *(const float4*)&ctx_w[q * 4];
    __syncthreads();
    const int kt = blockIdx.x;
    const int kr = threadIdx.x >> 3;       // 0..31 row within k-tile
    const int n0 = (threadIdx.x & 7) * 16; // 16 output cols per thread
    const int k = kt * 32 + kr;
    float acc[16];
#pragma unroll
    for (int j = 0; j < 16; ++j) acc[j] = 0.f;
    if (k < 768) {
        const float* wrow = emb_w + k * 64;
        for (int c = 0; c < 64; ++c) {
            const float a = wrow[c];
            const float* cx = &sctx[c * 128 + n0];
#pragma unroll
            for (int j = 0; j < 16; ++j) acc[j] = fmaf(a, cx[j], acc[j]);
        }
    } else {
        const float* wrow = tri_w + (k - 768) * 32;
        for (int c = 0; c < 32; ++c) {
            const float a = wrow[c];
            const float* cx = &sctx[(64 + c) * 128 + n0];
#pragma unroll
            for (int j = 0; j < 16; ++j) acc[j] = fmaf(a, cx[j], acc[j]);
        }
    }
    const int nt = threadIdx.x & 7;
    const int lanehi = (kr >> 3) << 4;
    const int j8 = kr & 7;
#pragma unroll
    for (int q = 0; q < 16; ++q) {
        const int lane = lanehi | q;
        g_wf[((kt * 8 + nt) * 64 + lane) * 8 + j8] = f2bf_rne(acc[q]);
    }
}

// ---------------------------------------------------------------------------
// k_front_mfma: x = [emb|tri] @ [E;T] + rm (x) wr + b_eff via bf16 MFMA.
// Wave = 32 rows x 128 cols (2 m-tiles x 8 n-tiles, K=1792). No LDS, no
// barriers: A direct f32 loads + on-the-fly bf16 cast, B pre-swizzled bf16.
// ---------------------------------------------------------------------------
__global__ __launch_bounds__(256) void k_front_mfma(const float* __restrict__ emb,
                                                    const float* __restrict__ tri,
                                                    const float* __restrict__ rm) {
    const int tid = threadIdx.x;
    const int lane = tid & 63, wid = tid >> 6;
    const int m0 = blockIdx.x * 128 + wid * 32;
    const int arow = lane & 15;   // M row within 16-tile
    const int kgrp = lane >> 4;   // k-group (8 elems each)

    f32x4 acc[2][8];
#pragma unroll
    for (int mi = 0; mi < 2; ++mi)
#pragma unroll
        for (int nt = 0; nt < 8; ++nt) {
            f32x4 z = {0.f, 0.f, 0.f, 0.f};
            acc[mi][nt] = z;
        }

    const float* embp = emb + (size_t)(m0 + arow) * 768 + kgrp * 8;
    const float* trip = tri + (size_t)(m0 + arow) * 1024 + kgrp * 8;

    for (int ks = 0; ks < 56; ++ks) {
        const float* s0 = (ks < 24) ? (embp + ks * 32) : (trip + (ks - 24) * 32);
        const int rstride = (ks < 24) ? 768 : 1024;
        const float4 f0 = *(const float4*)s0;
        const float4 f1 = *(const float4*)(s0 + 4);
        const float4 f2 = *(const float4*)(s0 + (size_t)16 * rstride);
        const float4 f3 = *(const float4*)(s0 + (size_t)16 * rstride + 4);
        v8bf a0, a1;
        a0[0] = (__bf16)f0.x; a0[1] = (__bf16)f0.y; a0[2] = (__bf16)f0.z; a0[3] = (__bf16)f0.w;
        a0[4] = (__bf16)f1.x; a0[5] = (__bf16)f1.y; a0[6] = (__bf16)f1.z; a0[7] = (__bf16)f1.w;
        a1[0] = (__bf16)f2.x; a1[1] = (__bf16)f2.y; a1[2] = (__bf16)f2.z; a1[3] = (__bf16)f2.w;
        a1[4] = (__bf16)f3.x; a1[5] = (__bf16)f3.y; a1[6] = (__bf16)f3.z; a1[7] = (__bf16)f3.w;
        const unsigned short* wks = g_wf + (size_t)ks * 4096 + lane * 8;
#pragma unroll
        for (int nt = 0; nt < 8; ++nt) {
            const v8bf b = *(const v8bf*)(wks + nt * 512);
            acc[0][nt] = __builtin_amdgcn_mfma_f32_16x16x32_bf16(a0, b, acc[0][nt], 0, 0, 0);
            acc[1][nt] = __builtin_amdgcn_mfma_f32_16x16x32_bf16(a1, b, acc[1][nt], 0, 0, 0);
        }
    }

    // epilogue: + rm*wr + b_eff, write g_x.  C/D: col=lane&15, row=(lane>>4)*4+reg.
    const int col0 = lane & 15;
    const int rbase = kgrp * 4;
#pragma unroll
    for (int mi = 0; mi < 2; ++mi) {
        const int rowb = m0 + mi * 16 + rbase;
        const f32x4 rv = *(const f32x4*)&rm[rowb];
#pragma unroll
        for (int nt = 0; nt < 8; ++nt) {
            const int col = nt * 16 + col0;
            const float be = g_beff[col];
            const float wv = g_wr[col];
#pragma unroll
            for (int rr = 0; rr < 4; ++rr) {
                g_x[(size_t)(rowb + rr) * 128 + col] = acc[mi][nt][rr] + rv[rr] * wv + be;
            }
        }
    }
}

// ---------------------------------------------------------------------------
// k_relay: 2 relay layers + head + output writes (unchanged from round 1).
// ---------------------------------------------------------------------------
__global__ __launch_bounds__(256) void k_relay(
    const float* __restrict__ pw_w2, const float* __restrict__ pw_b2,
    const float* __restrict__ pwn_g, const float* __restrict__ pwn_b,
    const float* __restrict__ gates, const float* __restrict__ norm_g,
    const float* __restrict__ norm_b, const float* __restrict__ head_w1,
    const float* __restrict__ head_b1, const float* __restrict__ head_w2,
    const float* __restrict__ head_b2, const float* __restrict__ stats_bias,
    float* __restrict__ out) {
    __shared__ __align__(16) float s_M[8 * 1028];
    __shared__ __align__(16) float s_w2[8 * 1028];
    __shared__ __align__(16) float s_b1p[8 * 68];
    __shared__ __align__(16) float s_hw1[8 * 132];
    __shared__ float s_hb1[64], s_hw2[64], s_hcb[8];
    __shared__ float s_mc[32 * 8];
    const int tid = threadIdx.x;
    const int r = tid >> 3, p = tid & 7;
    const int row = blockIdx.x * 32 + r;

    {   // stage head weights (256 float4 == 1024 floats exactly)
        const int e = tid * 4, pp = e >> 7, rem = e & 127;
        *(float4*)&s_hw1[pp * 132 + rem] = *(const float4*)&head_w1[e];
    }
    if (tid < 64) { s_hb1[tid] = head_b1[tid]; s_hw2[tid] = head_w2[tid]; }
    if (tid < 8) s_hcb[tid] = head_b2[tid] + stats_bias[tid];

    float x[16];
    {
        const float* xp = g_x + (size_t)row * 128 + p * 16;
#pragma unroll
        for (int i = 0; i < 4; ++i) *(float4*)&x[i * 4] = *(const float4*)&xp[i * 4];
    }

    for (int l = 0; l < 2; ++l) {
        if (l) __syncthreads();
        for (int q = tid; q < 2048; q += 256) {
            const int e = q * 4, pp = e >> 10, rem = e & 1023;
            *(float4*)&s_M[pp * 1028 + rem] = *(const float4*)&g_M[l * 8192 + e];
            *(float4*)&s_w2[pp * 1028 + rem] = *(const float4*)&pw_w2[l * 8192 + e];
        }
        if (tid < 128) {
            const int e = tid * 4, pp = e >> 6, rem = e & 63;
            *(float4*)&s_b1p[pp * 68 + rem] = *(const float4*)&g_b1p[l * 512 + e];
        }
        __syncthreads();

        // LayerNorm over the 128-dim row (8 lanes of same row cooperate)
        float sum = 0.f, sq = 0.f;
#pragma unroll
        for (int i = 0; i < 16; ++i) { sum += x[i]; sq = fmaf(x[i], x[i], sq); }
#pragma unroll
        for (int m = 1; m < 8; m <<= 1) {
            sum += __shfl_xor(sum, m, 64);
            sq += __shfl_xor(sq, m, 64);
        }
        const float mu = sum * (1.f / 128.f);
        const float rstd = rsqrtf(fmaxf(sq * (1.f / 128.f) - mu * mu, 0.f) + 1e-5f);
        float patch[16], n2 = 0.f;
#pragma unroll
        for (int i = 0; i < 16; ++i) {
            const float v = (x[i] - mu) * rstd * norm_g[l * 128 + p * 16 + i] + norm_b[l * 128 + p * 16 + i];
            patch[i] = v;
            n2 = fmaf(v, v, n2);
        }
        const float inv = 1.f / fmaxf(sqrtf(n2), 1e-12f);
        float pn[16];
#pragma unroll
        for (int i = 0; i < 16; ++i) pn[i] = -patch[i] * inv;  // negated for fnma form
        float pw[16];
#pragma unroll
        for (int i = 0; i < 16; ++i) pw[i] = pw_b2[(l * 8 + p) * 16 + i];
        const float* Mp = &s_M[p * 1028];
        const float* W2p = &s_w2[p * 1028];
        const float* Bp = &s_b1p[p * 68];
        for (int h4 = 0; h4 < 16; ++h4) {
            float a[4];
            *(float4*)a = *(const float4*)&Bp[h4 * 4];
#pragma unroll
            for (int d = 0; d < 16; ++d) {
                float m[4];
                *(float4*)m = *(const float4*)&Mp[d * 64 + h4 * 4];
#pragma unroll
                for (int j = 0; j < 4; ++j) a[j] = fmaf(pn[d], m[j], a[j]);
            }
#pragma unroll
            for (int j = 0; j < 4; ++j) {
                const float g = gelu_f(a[j]);
                float w[16];
#pragma unroll
                for (int u = 0; u < 4; ++u)
                    *(float4*)&w[u * 4] = *(const float4*)&W2p[(h4 * 4 + j) * 16 + u * 4];
#pragma unroll
                for (int u = 0; u < 16; ++u) pw[u] = fmaf(g, w[u], pw[u]);
            }
        }
        // LN16 on pw, gate, residual combine
        float s2 = 0.f, q2 = 0.f;
#pragma unroll
        for (int i = 0; i < 16; ++i) { s2 += pw[i]; q2 = fmaf(pw[i], pw[i], q2); }
        const float mu2 = s2 * (1.f / 16.f);
        const float rs2 = rsqrtf(fmaxf(q2 * (1.f / 16.f) - mu2 * mu2, 0.f) + 1e-5f);
        const float gate = 1.f / (1.f + expf(-gates[l * 8 + p]));
#pragma unroll
        for (int i = 0; i < 16; ++i) {
            const float v = (pw[i] - mu2) * rs2 * pwn_g[l * 16 + i] + pwn_b[l * 16 + i];
            x[i] = x[i] + gate * v + (1.f - gate) * patch[i];
        }
    }

    // head: per (row, patch) fully thread-local
    float accm = s_hcb[p];
#pragma unroll
    for (int j = 0; j < 8; ++j) {
        float a = s_hb1[p * 8 + j];
#pragma unroll
        for (int d = 0; d < 16; ++d) a = fmaf(x[d], s_hw1[p * 132 + d * 8 + j], a);
        accm = fmaf(gelu_f(a), s_hw2[p * 8 + j], accm);
    }
    const float mc = 0.1f + 4.9f / (1.f + expf(-accm));
    s_mc[r * 8 + p] = mc;
    out[(size_t)33554432 + (size_t)row * 8 + p] = mc;
    __syncthreads();

    // mag = repeat(mc, 128): cooperative fully-coalesced float4 writes
    const size_t base = (size_t)blockIdx.x * 32 * 1024;
#pragma unroll
    for (int it = 0; it < 32; ++it) {
        const int idx = it * 256 + tid;
        const int rr = idx >> 8, c4 = idx & 255;
        const float v = s_mc[rr * 8 + (c4 >> 5)];
        const float4 vv = make_float4(v, v, v, v);
        *(float4*)&out[base + rr * 1024 + c4 * 4] = vv;
    }
}

// ---------------------------------------------------------------------------
extern "C" void kernel_launch(void* const* d_in, const int* in_sizes, int n_in,
                              void* d_out, int out_size, void* d_ws, size_t ws_size,
                              hipStream_t stream) {
    (void)in_sizes; (void)n_in; (void)d_ws; (void)ws_size; (void)out_size;
    const float* emb = (const float*)d_in[0];
    const float* tria = (const float*)d_in[1];
    const float* rm = (const float*)d_in[2];
    const float* emb_w = (const float*)d_in[3];
    const float* emb_b = (const float*)d_in[4];
    const float* tri_w = (const float*)d_in[5];
    const float* tri_b = (const float*)d_in[6];
    const float* ctx_w = (const float*)d_in[7];
    const float* ctx_b = (const float*)d_in[8];
    const float* home = (const float*)d_in[9];
    const float* anch = (const float*)d_in[10];
    const float* pw_w1 = (const float*)d_in[11];
    const float* pw_b1 = (const float*)d_in[12];
    const float* pw_w2 = (const float*)d_in[13];
    const float* pw_b2 = (const float*)d_in[14];
    const float* pwn_g = (const float*)d_in[15];
    const float* pwn_b = (const float*)d_in[16];
    const float* gates = (const float*)d_in[17];
    const float* norm_g = (const float*)d_in[18];
    const float* norm_b = (const float*)d_in[19];
    const float* hw1 = (const float*)d_in[20];
    const float* hb1 = (const float*)d_in[21];
    const float* hw2 = (const float*)d_in[22];
    const float* hb2 = (const float*)d_in[23];
    const float* sb = (const float*)d_in[24];
    float* out = (float*)d_out;

    k_pre<<<16, 64, 0, stream>>>(home, anch, pw_w1, pw_b1);
    k_fold<<<57, 256, 0, stream>>>(emb_w, tri_w, ctx_w, ctx_b, emb_b, tri_b);
    k_front_mfma<<<256, 256, 0, stream>>>(emb, tria, rm);
    k_relay<<<1024, 256, 0, stream>>>(pw_w2, pw_b2, pwn_g, pwn_b, gates, norm_g, norm_b,
                                      hw1, hb1, hw2, hb2, sb, out);
}

// Round 3
// 203.967 us; speedup vs baseline: 1.0679x; 1.0530x over previous
//
#include <hip/hip_runtime.h>
#include <hip/hip_bf16.h>
#include <math.h>

#define BTOT 32768

typedef float f32x4 __attribute__((ext_vector_type(4)));
typedef __bf16 v8bf __attribute__((ext_vector_type(8)));

// Scratch in device globals (graph-capture safe).
__device__ float g_x[BTOT * 128];                       // 16.8 MB intermediate
__device__ float g_M[2 * 8 * 16 * 64];                  // folded AT^T @ pw_w1
__device__ float g_b1p[2 * 8 * 64];                     // pw_b1 + colsum(pw_w1)
__device__ __align__(16) unsigned short g_wf[1792 * 128]; // [E;T] bf16, B-fragment-swizzled
__device__ float g_beff[128];                           // ctx_b + emb_b@Wc1 + tri_b@Wc2
__device__ float g_wr[128];                             // ctx_w row 96 (rm column)

__device__ __forceinline__ float gelu_f(float v) {
    return 0.5f * v * (1.0f + erff(v * 0.70710678118654752f));
}

__device__ __forceinline__ unsigned short f2bf_rne(float x) {
    unsigned u = __float_as_uint(x);
    u += 0x7fffu + ((u >> 16) & 1u);
    return (unsigned short)(u >> 16);
}

// ---------------------------------------------------------------------------
// k_pre: per (l,p): slerp anchors -> fold AT^T @ pw_w1 into g_M, g_b1p.
// ---------------------------------------------------------------------------
__global__ __launch_bounds__(64) void k_pre(const float* __restrict__ home,
                                            const float* __restrict__ anchors,
                                            const float* __restrict__ pw_w1,
                                            const float* __restrict__ pw_b1) {
    __shared__ float s_AT[48 * 16];
    const int lp = blockIdx.x;   // 0..15  (l*8+p)
    const int tid = threadIdx.x; // 0..63
    if (tid < 48) {
        const int t = tid >> 4, a = tid & 15;
        const float* hp = home + (lp * 16 + a) * 16;
        const float* cp = anchors + (lp * 16 + a) * 16;
        float h[16], c[16], nh = 0.f, nc = 0.f;
#pragma unroll
        for (int i = 0; i < 16; ++i) {
            h[i] = hp[i]; nh = fmaf(h[i], h[i], nh);
            c[i] = cp[i]; nc = fmaf(c[i], c[i], nc);
        }
        const float ih = 1.f / fmaxf(sqrtf(nh), 1e-12f);
        const float ic = 1.f / fmaxf(sqrtf(nc), 1e-12f);
        float cw = 0.f;
#pragma unroll
        for (int i = 0; i < 16; ++i) { h[i] *= ih; c[i] *= ic; cw = fmaf(h[i], c[i], cw); }
        cw = fminf(fmaxf(cw, -1.f + 1e-7f), 1.f - 1e-7f);
        const float om = acosf(cw);
        const float so = fmaxf(sinf(om), 1e-7f);
        const float tt = (float)t * (1.f / 3.f);
        const float s1 = sinf((1.f - tt) * om), s2 = sinf(tt * om);
        float v[16], nv = 0.f;
#pragma unroll
        for (int i = 0; i < 16; ++i) { v[i] = (s1 * h[i] + s2 * c[i]) / so; nv = fmaf(v[i], v[i], nv); }
        const float iv = 1.f / fmaxf(sqrtf(nv), 1e-12f);
#pragma unroll
        for (int i = 0; i < 16; ++i) s_AT[tid * 16 + i] = v[i] * iv;
    }
    __syncthreads();
    const int h = tid;
    const float* w1 = pw_w1 + lp * 48 * 64;
    float b = pw_b1[lp * 64 + h];
    float m[16];
#pragma unroll
    for (int d = 0; d < 16; ++d) m[d] = 0.f;
    for (int j = 0; j < 48; ++j) {
        const float w = w1[j * 64 + h];
        b += w;
#pragma unroll
        for (int d = 0; d < 16; ++d) m[d] = fmaf(s_AT[j * 16 + d], w, m[d]);
    }
    g_b1p[lp * 64 + h] = b;
#pragma unroll
    for (int d = 0; d < 16; ++d) g_M[(lp * 16 + d) * 64 + h] = m[d];
}

// ---------------------------------------------------------------------------
// k_fold: W = [emb_w@Wc1 ; tri_w@Wc2] (1792x128) -> bf16, swizzled into MFMA
// B-fragment-linear order: g_wf[((kt*8+nt)*64 + lane)*8 + j] =
//   W[kt*32 + (lane>>4)*8 + j][nt*16 + (lane&15)].
// Block 56 also computes b_eff and wr.
// ---------------------------------------------------------------------------
__global__ __launch_bounds__(256) void k_fold(const float* __restrict__ emb_w,
                                              const float* __restrict__ tri_w,
                                              const float* __restrict__ ctx_w,
                                              const float* __restrict__ ctx_b,
                                              const float* __restrict__ emb_b,
                                              const float* __restrict__ tri_b) {
    if (blockIdx.x == 56) {
        const int n = threadIdx.x;
        if (n < 128) {
            float b = ctx_b[n];
            for (int c = 0; c < 64; ++c) b = fmaf(emb_b[c], ctx_w[c * 128 + n], b);
            for (int c = 0; c < 32; ++c) b = fmaf(tri_b[c], ctx_w[(64 + c) * 128 + n], b);
            g_beff[n] = b;
            g_wr[n] = ctx_w[96 * 128 + n];
        }
        return;
    }
    __shared__ float sctx[97 * 128];
    for (int q = threadIdx.x; q < 3104; q += 256)
        *(float4*)&sctx[q * 4] = *(const float4*)&ctx_w[q * 4];
    __syncthreads();
    const int kt = blockIdx.x;
    const int kr = threadIdx.x >> 3;       // 0..31 row within k-tile
    const int n0 = (threadIdx.x & 7) * 16; // 16 output cols per thread
    const int k = kt * 32 + kr;
    float acc[16];
#pragma unroll
    for (int j = 0; j < 16; ++j) acc[j] = 0.f;
    if (k < 768) {
        const float* wrow = emb_w + k * 64;
        for (int c = 0; c < 64; ++c) {
            const float a = wrow[c];
            const float* cx = &sctx[c * 128 + n0];
#pragma unroll
            for (int j = 0; j < 16; ++j) acc[j] = fmaf(a, cx[j], acc[j]);
        }
    } else {
        const float* wrow = tri_w + (k - 768) * 32;
        for (int c = 0; c < 32; ++c) {
            const float a = wrow[c];
            const float* cx = &sctx[(64 + c) * 128 + n0];
#pragma unroll
            for (int j = 0; j < 16; ++j) acc[j] = fmaf(a, cx[j], acc[j]);
        }
    }
    const int nt = threadIdx.x & 7;
    const int lanehi = (kr >> 3) << 4;
    const int j8 = kr & 7;
#pragma unroll
    for (int q = 0; q < 16; ++q) {
        const int lane = lanehi | q;
        g_wf[((kt * 8 + nt) * 64 + lane) * 8 + j8] = f2bf_rne(acc[q]);
    }
}

// ---------------------------------------------------------------------------
// k_front_mfma: x = [emb|tri] @ [E;T] + rm (x) wr + b_eff via bf16 MFMA.
// Wave = 16 rows x 128 cols (1 m-tile x 8 n-tiles, K=1792 in 56 steps of 32).
// 2048 waves (8/CU) for TLP. Pair-unrolled K-loop: per pair, issue order is
// [B(2p) x8, B(2p+1) x8, A(next pair) x4] then compute both steps, so the
// counted vmcnt waits for B never drain the A prefetch (stays in flight a
// full pair, ~400 cyc of hiding), and B waits are batched (1 per step).
// ---------------------------------------------------------------------------
__global__ __launch_bounds__(256) void k_front_mfma(const float* __restrict__ emb,
                                                    const float* __restrict__ tri,
                                                    const float* __restrict__ rm) {
    const int tid = threadIdx.x;
    const int lane = tid & 63, wid = tid >> 6;
    const int m0 = blockIdx.x * 64 + wid * 16;
    const int arow = lane & 15;   // M row within 16-tile
    const int kgrp = lane >> 4;   // k-group (8 elems each)

    f32x4 acc[8];
#pragma unroll
    for (int nt = 0; nt < 8; ++nt) {
        f32x4 z = {0.f, 0.f, 0.f, 0.f};
        acc[nt] = z;
    }

    const float* embp = emb + (size_t)(m0 + arow) * 768 + kgrp * 8;
    const float* trip = tri + (size_t)(m0 + arow) * 1024 + kgrp * 8;

#define ALOAD(b0, b1, kk) { \
        const int k_ = (kk) < 55 ? (kk) : 55; \
        const float* s_ = (k_ < 24) ? (embp + k_ * 32) : (trip + (k_ - 24) * 32); \
        b0 = *(const float4*)s_; b1 = *(const float4*)(s_ + 4); }

#define BLOAD(bb, kk) { \
        const unsigned short* w_ = g_wf + (size_t)(kk) * 4096 + lane * 8; \
        _Pragma("unroll") \
        for (int nt = 0; nt < 8; ++nt) bb[nt] = *(const v8bf*)(w_ + nt * 512); }

#define STEP(f0, f1, bb) { \
        v8bf a_; \
        a_[0] = (__bf16)f0.x; a_[1] = (__bf16)f0.y; a_[2] = (__bf16)f0.z; a_[3] = (__bf16)f0.w; \
        a_[4] = (__bf16)f1.x; a_[5] = (__bf16)f1.y; a_[6] = (__bf16)f1.z; a_[7] = (__bf16)f1.w; \
        _Pragma("unroll") \
        for (int nt = 0; nt < 8; ++nt) \
            acc[nt] = __builtin_amdgcn_mfma_f32_16x16x32_bf16(a_, bb[nt], acc[nt], 0, 0, 0); }

    float4 ac0, ac1, ac2, ac3;   // A for current pair (steps 2p, 2p+1)
    float4 an0, an1, an2, an3;   // A for next pair
    v8bf bb0[8], bb1[8];

    ALOAD(ac0, ac1, 0);
    ALOAD(ac2, ac3, 1);

    for (int p = 0; p < 28; ++p) {
        const int ks = p * 2;
        BLOAD(bb0, ks);
        BLOAD(bb1, ks + 1);
        ALOAD(an0, an1, ks + 2);
        ALOAD(an2, an3, ks + 3);
        STEP(ac0, ac1, bb0);
        STEP(ac2, ac3, bb1);
        ac0 = an0; ac1 = an1; ac2 = an2; ac3 = an3;
    }
#undef ALOAD
#undef BLOAD
#undef STEP

    // epilogue: + rm*wr + b_eff, write g_x.  C/D: col=lane&15, row=(lane>>4)*4+reg.
    const int col0 = lane & 15;
    const int rowb = m0 + kgrp * 4;
    const f32x4 rv = *(const f32x4*)&rm[rowb];
#pragma unroll
    for (int nt = 0; nt < 8; ++nt) {
        const int col = nt * 16 + col0;
        const float be = g_beff[col];
        const float wv = g_wr[col];
#pragma unroll
        for (int rr = 0; rr < 4; ++rr) {
            g_x[(size_t)(rowb + rr) * 128 + col] = acc[nt][rr] + rv[rr] * wv + be;
        }
    }
}

// ---------------------------------------------------------------------------
// k_relay: 2 relay layers + head + output writes (unchanged).
// ---------------------------------------------------------------------------
__global__ __launch_bounds__(256) void k_relay(
    const float* __restrict__ pw_w2, const float* __restrict__ pw_b2,
    const float* __restrict__ pwn_g, const float* __restrict__ pwn_b,
    const float* __restrict__ gates, const float* __restrict__ norm_g,
    const float* __restrict__ norm_b, const float* __restrict__ head_w1,
    const float* __restrict__ head_b1, const float* __restrict__ head_w2,
    const float* __restrict__ head_b2, const float* __restrict__ stats_bias,
    float* __restrict__ out) {
    __shared__ __align__(16) float s_M[8 * 1028];
    __shared__ __align__(16) float s_w2[8 * 1028];
    __shared__ __align__(16) float s_b1p[8 * 68];
    __shared__ __align__(16) float s_hw1[8 * 132];
    __shared__ float s_hb1[64], s_hw2[64], s_hcb[8];
    __shared__ float s_mc[32 * 8];
    const int tid = threadIdx.x;
    const int r = tid >> 3, p = tid & 7;
    const int row = blockIdx.x * 32 + r;

    {   // stage head weights (256 float4 == 1024 floats exactly)
        const int e = tid * 4, pp = e >> 7, rem = e & 127;
        *(float4*)&s_hw1[pp * 132 + rem] = *(const float4*)&head_w1[e];
    }
    if (tid < 64) { s_hb1[tid] = head_b1[tid]; s_hw2[tid] = head_w2[tid]; }
    if (tid < 8) s_hcb[tid] = head_b2[tid] + stats_bias[tid];

    float x[16];
    {
        const float* xp = g_x + (size_t)row * 128 + p * 16;
#pragma unroll
        for (int i = 0; i < 4; ++i) *(float4*)&x[i * 4] = *(const float4*)&xp[i * 4];
    }

    for (int l = 0; l < 2; ++l) {
        if (l) __syncthreads();
        for (int q = tid; q < 2048; q += 256) {
            const int e = q * 4, pp = e >> 10, rem = e & 1023;
            *(float4*)&s_M[pp * 1028 + rem] = *(const float4*)&g_M[l * 8192 + e];
            *(float4*)&s_w2[pp * 1028 + rem] = *(const float4*)&pw_w2[l * 8192 + e];
        }
        if (tid < 128) {
            const int e = tid * 4, pp = e >> 6, rem = e & 63;
            *(float4*)&s_b1p[pp * 68 + rem] = *(const float4*)&g_b1p[l * 512 + e];
        }
        __syncthreads();

        // LayerNorm over the 128-dim row (8 lanes of same row cooperate)
        float sum = 0.f, sq = 0.f;
#pragma unroll
        for (int i = 0; i < 16; ++i) { sum += x[i]; sq = fmaf(x[i], x[i], sq); }
#pragma unroll
        for (int m = 1; m < 8; m <<= 1) {
            sum += __shfl_xor(sum, m, 64);
            sq += __shfl_xor(sq, m, 64);
        }
        const float mu = sum * (1.f / 128.f);
        const float rstd = rsqrtf(fmaxf(sq * (1.f / 128.f) - mu * mu, 0.f) + 1e-5f);
        float patch[16], n2 = 0.f;
#pragma unroll
        for (int i = 0; i < 16; ++i) {
            const float v = (x[i] - mu) * rstd * norm_g[l * 128 + p * 16 + i] + norm_b[l * 128 + p * 16 + i];
            patch[i] = v;
            n2 = fmaf(v, v, n2);
        }
        const float inv = 1.f / fmaxf(sqrtf(n2), 1e-12f);
        float pn[16];
#pragma unroll
        for (int i = 0; i < 16; ++i) pn[i] = -patch[i] * inv;  // negated for fnma form
        float pw[16];
#pragma unroll
        for (int i = 0; i < 16; ++i) pw[i] = pw_b2[(l * 8 + p) * 16 + i];
        const float* Mp = &s_M[p * 1028];
        const float* W2p = &s_w2[p * 1028];
        const float* Bp = &s_b1p[p * 68];
        for (int h4 = 0; h4 < 16; ++h4) {
            float a[4];
            *(float4*)a = *(const float4*)&Bp[h4 * 4];
#pragma unroll
            for (int d = 0; d < 16; ++d) {
                float m[4];
                *(float4*)m = *(const float4*)&Mp[d * 64 + h4 * 4];
#pragma unroll
                for (int j = 0; j < 4; ++j) a[j] = fmaf(pn[d], m[j], a[j]);
            }
#pragma unroll
            for (int j = 0; j < 4; ++j) {
                const float g = gelu_f(a[j]);
                float w[16];
#pragma unroll
                for (int u = 0; u < 4; ++u)
                    *(float4*)&w[u * 4] = *(const float4*)&W2p[(h4 * 4 + j) * 16 + u * 4];
#pragma unroll
                for (int u = 0; u < 16; ++u) pw[u] = fmaf(g, w[u], pw[u]);
            }
        }
        // LN16 on pw, gate, residual combine
        float s2 = 0.f, q2 = 0.f;
#pragma unroll
        for (int i = 0; i < 16; ++i) { s2 += pw[i]; q2 = fmaf(pw[i], pw[i], q2); }
        const float mu2 = s2 * (1.f / 16.f);
        const float rs2 = rsqrtf(fmaxf(q2 * (1.f / 16.f) - mu2 * mu2, 0.f) + 1e-5f);
        const float gate = 1.f / (1.f + expf(-gates[l * 8 + p]));
#pragma unroll
        for (int i = 0; i < 16; ++i) {
            const float v = (pw[i] - mu2) * rs2 * pwn_g[l * 16 + i] + pwn_b[l * 16 + i];
            x[i] = x[i] + gate * v + (1.f - gate) * patch[i];
        }
    }

    // head: per (row, patch) fully thread-local
    float accm = s_hcb[p];
#pragma unroll
    for (int j = 0; j < 8; ++j) {
        float a = s_hb1[p * 8 + j];
#pragma unroll
        for (int d = 0; d < 16; ++d) a = fmaf(x[d], s_hw1[p * 132 + d * 8 + j], a);
        accm = fmaf(gelu_f(a), s_hw2[p * 8 + j], accm);
    }
    const float mc = 0.1f + 4.9f / (1.f + expf(-accm));
    s_mc[r * 8 + p] = mc;
    out[(size_t)33554432 + (size_t)row * 8 + p] = mc;
    __syncthreads();

    // mag = repeat(mc, 128): cooperative fully-coalesced float4 writes
    const size_t base = (size_t)blockIdx.x * 32 * 1024;
#pragma unroll
    for (int it = 0; it < 32; ++it) {
        const int idx = it * 256 + tid;
        const int rr = idx >> 8, c4 = idx & 255;
        const float v = s_mc[rr * 8 + (c4 >> 5)];
        const float4 vv = make_float4(v, v, v, v);
        *(float4*)&out[base + rr * 1024 + c4 * 4] = vv;
    }
}

// ---------------------------------------------------------------------------
extern "C" void kernel_launch(void* const* d_in, const int* in_sizes, int n_in,
                              void* d_out, int out_size, void* d_ws, size_t ws_size,
                              hipStream_t stream) {
    (void)in_sizes; (void)n_in; (void)d_ws; (void)ws_size; (void)out_size;
    const float* emb = (const float*)d_in[0];
    const float* tria = (const float*)d_in[1];
    const float* rm = (const float*)d_in[2];
    const float* emb_w = (const float*)d_in[3];
    const float* emb_b = (const float*)d_in[4];
    const float* tri_w = (const float*)d_in[5];
    const float* tri_b = (const float*)d_in[6];
    const float* ctx_w = (const float*)d_in[7];
    const float* ctx_b = (const float*)d_in[8];
    const float* home = (const float*)d_in[9];
    const float* anch = (const float*)d_in[10];
    const float* pw_w1 = (const float*)d_in[11];
    const float* pw_b1 = (const float*)d_in[12];
    const float* pw_w2 = (const float*)d_in[13];
    const float* pw_b2 = (const float*)d_in[14];
    const float* pwn_g = (const float*)d_in[15];
    const float* pwn_b = (const float*)d_in[16];
    const float* gates = (const float*)d_in[17];
    const float* norm_g = (const float*)d_in[18];
    const float* norm_b = (const float*)d_in[19];
    const float* hw1 = (const float*)d_in[20];
    const float* hb1 = (const float*)d_in[21];
    const float* hw2 = (const float*)d_in[22];
    const float* hb2 = (const float*)d_in[23];
    const float* sb = (const float*)d_in[24];
    float* out = (float*)d_out;

    k_pre<<<16, 64, 0, stream>>>(home, anch, pw_w1, pw_b1);
    k_fold<<<57, 256, 0, stream>>>(emb_w, tri_w, ctx_w, ctx_b, emb_b, tri_b);
    k_front_mfma<<<512, 256, 0, stream>>>(emb, tria, rm);
    k_relay<<<1024, 256, 0, stream>>>(pw_w2, pw_b2, pwn_g, pwn_b, gates, norm_g, norm_b,
                                      hw1, hb1, hw2, hb2, sb, out);
}

// Round 5
// 187.569 us; speedup vs baseline: 1.1612x; 1.0874x over previous
//
#include <hip/hip_runtime.h>
#include <hip/hip_bf16.h>
#include <math.h>

#define BTOT 32768

typedef float f32x4 __attribute__((ext_vector_type(4)));
typedef __bf16 v8bf __attribute__((ext_vector_type(8)));

// Scratch in device globals (graph-capture safe).
__device__ float g_x[BTOT * 128];                       // 16.8 MB intermediate
__device__ float g_M[2 * 8 * 16 * 64];                  // folded AT^T @ pw_w1
__device__ float g_b1p[2 * 8 * 64];                     // pw_b1 + colsum(pw_w1)
__device__ __align__(16) unsigned short g_wf[1792 * 128]; // [E;T] bf16, B-fragment-swizzled
__device__ float g_beff[128];                           // ctx_b + emb_b@Wc1 + tri_b@Wc2
__device__ float g_wr[128];                             // ctx_w row 96 (rm column)

__device__ __forceinline__ float gelu_f(float v) {
    return 0.5f * v * (1.0f + erff(v * 0.70710678118654752f));
}

__device__ __forceinline__ unsigned short f2bf_rne(float x) {
    unsigned u = __float_as_uint(x);
    u += 0x7fffu + ((u >> 16) & 1u);
    return (unsigned short)(u >> 16);
}

#define GLOAD16(gp, lp)                                                        \
    __builtin_amdgcn_global_load_lds(                                          \
        (const __attribute__((address_space(1))) void*)(gp),                   \
        (__attribute__((address_space(3))) void*)(lp), 16, 0, 0)

// ---------------------------------------------------------------------------
// k_pre: per (l,p): slerp anchors -> fold AT^T @ pw_w1 into g_M, g_b1p.
// ---------------------------------------------------------------------------
__global__ __launch_bounds__(64) void k_pre(const float* __restrict__ home,
                                            const float* __restrict__ anchors,
                                            const float* __restrict__ pw_w1,
                                            const float* __restrict__ pw_b1) {
    __shared__ float s_AT[48 * 16];
    const int lp = blockIdx.x;   // 0..15  (l*8+p)
    const int tid = threadIdx.x; // 0..63
    if (tid < 48) {
        const int t = tid >> 4, a = tid & 15;
        const float* hp = home + (lp * 16 + a) * 16;
        const float* cp = anchors + (lp * 16 + a) * 16;
        float h[16], c[16], nh = 0.f, nc = 0.f;
#pragma unroll
        for (int i = 0; i < 16; ++i) {
            h[i] = hp[i]; nh = fmaf(h[i], h[i], nh);
            c[i] = cp[i]; nc = fmaf(c[i], c[i], nc);
        }
        const float ih = 1.f / fmaxf(sqrtf(nh), 1e-12f);
        const float ic = 1.f / fmaxf(sqrtf(nc), 1e-12f);
        float cw = 0.f;
#pragma unroll
        for (int i = 0; i < 16; ++i) { h[i] *= ih; c[i] *= ic; cw = fmaf(h[i], c[i], cw); }
        cw = fminf(fmaxf(cw, -1.f + 1e-7f), 1.f - 1e-7f);
        const float om = acosf(cw);
        const float so = fmaxf(sinf(om), 1e-7f);
        const float tt = (float)t * (1.f / 3.f);
        const float s1 = sinf((1.f - tt) * om), s2 = sinf(tt * om);
        float v[16], nv = 0.f;
#pragma unroll
        for (int i = 0; i < 16; ++i) { v[i] = (s1 * h[i] + s2 * c[i]) / so; nv = fmaf(v[i], v[i], nv); }
        const float iv = 1.f / fmaxf(sqrtf(nv), 1e-12f);
#pragma unroll
        for (int i = 0; i < 16; ++i) s_AT[tid * 16 + i] = v[i] * iv;
    }
    __syncthreads();
    const int h = tid;
    const float* w1 = pw_w1 + lp * 48 * 64;
    float b = pw_b1[lp * 64 + h];
    float m[16];
#pragma unroll
    for (int d = 0; d < 16; ++d) m[d] = 0.f;
    for (int j = 0; j < 48; ++j) {
        const float w = w1[j * 64 + h];
        b += w;
#pragma unroll
        for (int d = 0; d < 16; ++d) m[d] = fmaf(s_AT[j * 16 + d], w, m[d]);
    }
    g_b1p[lp * 64 + h] = b;
#pragma unroll
    for (int d = 0; d < 16; ++d) g_M[(lp * 16 + d) * 64 + h] = m[d];
}

// ---------------------------------------------------------------------------
// k_fold: W = [emb_w@Wc1 ; tri_w@Wc2] (1792x128) -> bf16, swizzled into MFMA
// B-fragment-linear order: g_wf[((kt*8+nt)*64 + lane)*8 + j] =
//   W[kt*32 + (lane>>4)*8 + j][nt*16 + (lane&15)].
// Block 56 also computes b_eff and wr.
// ---------------------------------------------------------------------------
__global__ __launch_bounds__(256) void k_fold(const float* __restrict__ emb_w,
                                              const float* __restrict__ tri_w,
                                              const float* __restrict__ ctx_w,
                                              const float* __restrict__ ctx_b,
                                              const float* __restrict__ emb_b,
                                              const float* __restrict__ tri_b) {
    if (blockIdx.x == 56) {
        const int n = threadIdx.x;
        if (n < 128) {
            float b = ctx_b[n];
            for (int c = 0; c < 64; ++c) b = fmaf(emb_b[c], ctx_w[c * 128 + n], b);
            for (int c = 0; c < 32; ++c) b = fmaf(tri_b[c], ctx_w[(64 + c) * 128 + n], b);
            g_beff[n] = b;
            g_wr[n] = ctx_w[96 * 128 + n];
        }
        return;
    }
    __shared__ float sctx[97 * 128];
    for (int q = threadIdx.x; q < 3104; q += 256)
        *(float4*)&sctx[q * 4] = *(const float4*)&ctx_w[q * 4];
    __syncthreads();
    const int kt = blockIdx.x;
    const int kr = threadIdx.x >> 3;       // 0..31 row within k-tile
    const int n0 = (threadIdx.x & 7) * 16; // 16 output cols per thread
    const int k = kt * 32 + kr;
    float acc[16];
#pragma unroll
    for (int j = 0; j < 16; ++j) acc[j] = 0.f;
    if (k < 768) {
        const float* wrow = emb_w + k * 64;
        for (int c = 0; c < 64; ++c) {
            const float a = wrow[c];
            const float* cx = &sctx[c * 128 + n0];
#pragma unroll
            for (int j = 0; j < 16; ++j) acc[j] = fmaf(a, cx[j], acc[j]);
        }
    } else {
        const float* wrow = tri_w + (k - 768) * 32;
        for (int c = 0; c < 32; ++c) {
            const float a = wrow[c];
            const float* cx = &sctx[(64 + c) * 128 + n0];
#pragma unroll
            for (int j = 0; j < 16; ++j) acc[j] = fmaf(a, cx[j], acc[j]);
        }
    }
    const int nt = threadIdx.x & 7;
    const int lanehi = (kr >> 3) << 4;
    const int j8 = kr & 7;
#pragma unroll
    for (int q = 0; q < 16; ++q) {
        const int lane = lanehi | q;
        g_wf[((kt * 8 + nt) * 64 + lane) * 8 + j8] = f2bf_rne(acc[q]);
    }
}

// ---------------------------------------------------------------------------
// k_front_mfma (m97-style LDS-staged): x = [emb|tri]@[E;T] + rm(x)wr + b_eff.
// Block = 64 rows x 128 cols, 4 waves (16 rows each), K-tile 64, 28 tiles
// (tiles 0..11 from emb, 12..27 from tri). Double-buffered LDS: A f32 16KB
// (XOR-swizzled via pre-swizzled global src, mask (row&15)<<4) + B bf16 16KB
// (linear, fragment-order), staged with global_load_lds width=16 and
// wave-uniform LDS base (HW writes base + lane*16). One barrier per tile.
// ---------------------------------------------------------------------------
__global__ __launch_bounds__(256) void k_front_mfma(const float* __restrict__ emb,
                                                    const float* __restrict__ tri,
                                                    const float* __restrict__ rm) {
    __shared__ __align__(16) char lds[65536];   // A0 | A1 | B0 | B1 (16KB each)
    const int tid = threadIdx.x;
    const int lane = tid & 63, w = tid >> 6;
    const int row0 = blockIdx.x * 64;
    const int arow = lane & 15, kgrp = lane >> 4;

    f32x4 acc[8];
#pragma unroll
    for (int nt = 0; nt < 8; ++nt) {
        f32x4 z = {0.f, 0.f, 0.f, 0.f};
        acc[nt] = z;
    }

    // ---- staging: 4 B-issues + 4 A-issues per wave per tile (16B each lane)
#define STAGE(kc, buf) {                                                       \
        char* AbBase_ = lds + (buf) * 16384 + w * 4096;        /* uniform */   \
        char* BbBase_ = lds + 32768 + (buf) * 16384 + w * 4096;                \
        const char* gB_ = (const char*)g_wf + (size_t)(kc) * 16384             \
                          + w * 4096 + lane * 16;                              \
        _Pragma("unroll")                                                      \
        for (int i = 0; i < 4; ++i) GLOAD16(gB_ + i * 1024, BbBase_ + i * 1024); \
        _Pragma("unroll")                                                      \
        for (int i = 0; i < 4; ++i) {                                          \
            const int r_ = i * 4 + (lane >> 4);                                \
            const int grow_ = row0 + w * 16 + r_;                              \
            const int colb_ = ((lane & 15) * 16) ^ (r_ << 4);                  \
            const char* gA_ = ((kc) < 12)                                      \
                ? (const char*)(emb + (size_t)grow_ * 768 + (kc) * 64) + colb_ \
                : (const char*)(tri + (size_t)grow_ * 1024 + ((kc) - 12) * 64) + colb_; \
            GLOAD16(gA_, AbBase_ + i * 1024);                                  \
        }                                                                      \
    }

    // ---- compute one K-tile (64) from buffer buf
#define COMPUTE(buf) {                                                         \
        const char* Ar_ = lds + (buf) * 16384 + (w * 16 + arow) * 256;         \
        const char* Br_ = lds + 32768 + (buf) * 16384 + lane * 16;             \
        const int msk_ = arow << 4;                                            \
        _Pragma("unroll")                                                      \
        for (int h = 0; h < 2; ++h) {                                          \
            const int c0_ = h * 128 + kgrp * 32;                               \
            const float4 f0_ = *(const float4*)(Ar_ + (c0_ ^ msk_));           \
            const float4 f1_ = *(const float4*)(Ar_ + ((c0_ + 16) ^ msk_));    \
            v8bf a_;                                                           \
            a_[0] = (__bf16)f0_.x; a_[1] = (__bf16)f0_.y;                      \
            a_[2] = (__bf16)f0_.z; a_[3] = (__bf16)f0_.w;                      \
            a_[4] = (__bf16)f1_.x; a_[5] = (__bf16)f1_.y;                      \
            a_[6] = (__bf16)f1_.z; a_[7] = (__bf16)f1_.w;                      \
            const char* bp_ = Br_ + h * 8192;                                  \
            _Pragma("unroll")                                                  \
            for (int nt = 0; nt < 8; ++nt) {                                   \
                const v8bf b_ = *(const v8bf*)(bp_ + nt * 1024);               \
                acc[nt] = __builtin_amdgcn_mfma_f32_16x16x32_bf16(a_, b_, acc[nt], 0, 0, 0); \
            }                                                                  \
        }                                                                      \
    }

    STAGE(0, 0);
    __syncthreads();
    int buf = 0;
    for (int kc = 0; kc < 28; ++kc) {
        if (kc < 27) STAGE(kc + 1, buf ^ 1);
        COMPUTE(buf);
        __syncthreads();
        buf ^= 1;
    }
#undef STAGE
#undef COMPUTE

    // epilogue: + rm*wr + b_eff, write g_x.  C/D: col=lane&15, row=(lane>>4)*4+reg.
    const int rowb = row0 + w * 16 + kgrp * 4;
    const f32x4 rv = *(const f32x4*)&rm[rowb];
#pragma unroll
    for (int nt = 0; nt < 8; ++nt) {
        const int col = nt * 16 + arow;
        const float be = g_beff[col];
        const float wv = g_wr[col];
#pragma unroll
        for (int rr = 0; rr < 4; ++rr) {
            g_x[(size_t)(rowb + rr) * 128 + col] = acc[nt][rr] + rv[rr] * wv + be;
        }
    }
}

// ---------------------------------------------------------------------------
// k_relay: 2 relay layers + head + output writes (unchanged).
// ---------------------------------------------------------------------------
__global__ __launch_bounds__(256) void k_relay(
    const float* __restrict__ pw_w2, const float* __restrict__ pw_b2,
    const float* __restrict__ pwn_g, const float* __restrict__ pwn_b,
    const float* __restrict__ gates, const float* __restrict__ norm_g,
    const float* __restrict__ norm_b, const float* __restrict__ head_w1,
    const float* __restrict__ head_b1, const float* __restrict__ head_w2,
    const float* __restrict__ head_b2, const float* __restrict__ stats_bias,
    float* __restrict__ out) {
    __shared__ __align__(16) float s_M[8 * 1028];
    __shared__ __align__(16) float s_w2[8 * 1028];
    __shared__ __align__(16) float s_b1p[8 * 68];
    __shared__ __align__(16) float s_hw1[8 * 132];
    __shared__ float s_hb1[64], s_hw2[64], s_hcb[8];
    __shared__ float s_mc[32 * 8];
    const int tid = threadIdx.x;
    const int r = tid >> 3, p = tid & 7;
    const int row = blockIdx.x * 32 + r;

    {   // stage head weights (256 float4 == 1024 floats exactly)
        const int e = tid * 4, pp = e >> 7, rem = e & 127;
        *(float4*)&s_hw1[pp * 132 + rem] = *(const float4*)&head_w1[e];
    }
    if (tid < 64) { s_hb1[tid] = head_b1[tid]; s_hw2[tid] = head_w2[tid]; }
    if (tid < 8) s_hcb[tid] = head_b2[tid] + stats_bias[tid];

    float x[16];
    {
        const float* xp = g_x + (size_t)row * 128 + p * 16;
#pragma unroll
        for (int i = 0; i < 4; ++i) *(float4*)&x[i * 4] = *(const float4*)&xp[i * 4];
    }

    for (int l = 0; l < 2; ++l) {
        if (l) __syncthreads();
        for (int q = tid; q < 2048; q += 256) {
            const int e = q * 4, pp = e >> 10, rem = e & 1023;
            *(float4*)&s_M[pp * 1028 + rem] = *(const float4*)&g_M[l * 8192 + e];
            *(float4*)&s_w2[pp * 1028 + rem] = *(const float4*)&pw_w2[l * 8192 + e];
        }
        if (tid < 128) {
            const int e = tid * 4, pp = e >> 6, rem = e & 63;
            *(float4*)&s_b1p[pp * 68 + rem] = *(const float4*)&g_b1p[l * 512 + e];
        }
        __syncthreads();

        // LayerNorm over the 128-dim row (8 lanes of same row cooperate)
        float sum = 0.f, sq = 0.f;
#pragma unroll
        for (int i = 0; i < 16; ++i) { sum += x[i]; sq = fmaf(x[i], x[i], sq); }
#pragma unroll
        for (int m = 1; m < 8; m <<= 1) {
            sum += __shfl_xor(sum, m, 64);
            sq += __shfl_xor(sq, m, 64);
        }
        const float mu = sum * (1.f / 128.f);
        const float rstd = rsqrtf(fmaxf(sq * (1.f / 128.f) - mu * mu, 0.f) + 1e-5f);
        float patch[16], n2 = 0.f;
#pragma unroll
        for (int i = 0; i < 16; ++i) {
            const float v = (x[i] - mu) * rstd * norm_g[l * 128 + p * 16 + i] + norm_b[l * 128 + p * 16 + i];
            patch[i] = v;
            n2 = fmaf(v, v, n2);
        }
        const float inv = 1.f / fmaxf(sqrtf(n2), 1e-12f);
        float pn[16];
#pragma unroll
        for (int i = 0; i < 16; ++i) pn[i] = -patch[i] * inv;  // negated for fnma form
        float pw[16];
#pragma unroll
        for (int i = 0; i < 16; ++i) pw[i] = pw_b2[(l * 8 + p) * 16 + i];
        const float* Mp = &s_M[p * 1028];
        const float* W2p = &s_w2[p * 1028];
        const float* Bp = &s_b1p[p * 68];
        for (int h4 = 0; h4 < 16; ++h4) {
            float a[4];
            *(float4*)a = *(const float4*)&Bp[h4 * 4];
#pragma unroll
            for (int d = 0; d < 16; ++d) {
                float m[4];
                *(float4*)m = *(const float4*)&Mp[d * 64 + h4 * 4];
#pragma unroll
                for (int j = 0; j < 4; ++j) a[j] = fmaf(pn[d], m[j], a[j]);
            }
#pragma unroll
            for (int j = 0; j < 4; ++j) {
                const float g = gelu_f(a[j]);
                float w[16];
#pragma unroll
                for (int u = 0; u < 4; ++u)
                    *(float4*)&w[u * 4] = *(const float4*)&W2p[(h4 * 4 + j) * 16 + u * 4];
#pragma unroll
                for (int u = 0; u < 16; ++u) pw[u] = fmaf(g, w[u], pw[u]);
            }
        }
        // LN16 on pw, gate, residual combine
        float s2 = 0.f, q2 = 0.f;
#pragma unroll
        for (int i = 0; i < 16; ++i) { s2 += pw[i]; q2 = fmaf(pw[i], pw[i], q2); }
        const float mu2 = s2 * (1.f / 16.f);
        const float rs2 = rsqrtf(fmaxf(q2 * (1.f / 16.f) - mu2 * mu2, 0.f) + 1e-5f);
        const float gate = 1.f / (1.f + expf(-gates[l * 8 + p]));
#pragma unroll
        for (int i = 0; i < 16; ++i) {
            const float v = (pw[i] - mu2) * rs2 * pwn_g[l * 16 + i] + pwn_b[l * 16 + i];
            x[i] = x[i] + gate * v + (1.f - gate) * patch[i];
        }
    }

    // head: per (row, patch) fully thread-local
    float accm = s_hcb[p];
#pragma unroll
    for (int j = 0; j < 8; ++j) {
        float a = s_hb1[p * 8 + j];
#pragma unroll
        for (int d = 0; d < 16; ++d) a = fmaf(x[d], s_hw1[p * 132 + d * 8 + j], a);
        accm = fmaf(gelu_f(a), s_hw2[p * 8 + j], accm);
    }
    const float mc = 0.1f + 4.9f / (1.f + expf(-accm));
    s_mc[r * 8 + p] = mc;
    out[(size_t)33554432 + (size_t)row * 8 + p] = mc;
    __syncthreads();

    // mag = repeat(mc, 128): cooperative fully-coalesced float4 writes
    const size_t base = (size_t)blockIdx.x * 32 * 1024;
#pragma unroll
    for (int it = 0; it < 32; ++it) {
        const int idx = it * 256 + tid;
        const int rr = idx >> 8, c4 = idx & 255;
        const float v = s_mc[rr * 8 + (c4 >> 5)];
        const float4 vv = make_float4(v, v, v, v);
        *(float4*)&out[base + rr * 1024 + c4 * 4] = vv;
    }
}

// ---------------------------------------------------------------------------
extern "C" void kernel_launch(void* const* d_in, const int* in_sizes, int n_in,
                              void* d_out, int out_size, void* d_ws, size_t ws_size,
                              hipStream_t stream) {
    (void)in_sizes; (void)n_in; (void)d_ws; (void)ws_size; (void)out_size;
    const float* emb = (const float*)d_in[0];
    const float* tria = (const float*)d_in[1];
    const float* rm = (const float*)d_in[2];
    const float* emb_w = (const float*)d_in[3];
    const float* emb_b = (const float*)d_in[4];
    const float* tri_w = (const float*)d_in[5];
    const float* tri_b = (const float*)d_in[6];
    const float* ctx_w = (const float*)d_in[7];
    const float* ctx_b = (const float*)d_in[8];
    const float* home = (const float*)d_in[9];
    const float* anch = (const float*)d_in[10];
    const float* pw_w1 = (const float*)d_in[11];
    const float* pw_b1 = (const float*)d_in[12];
    const float* pw_w2 = (const float*)d_in[13];
    const float* pw_b2 = (const float*)d_in[14];
    const float* pwn_g = (const float*)d_in[15];
    const float* pwn_b = (const float*)d_in[16];
    const float* gates = (const float*)d_in[17];
    const float* norm_g = (const float*)d_in[18];
    const float* norm_b = (const float*)d_in[19];
    const float* hw1 = (const float*)d_in[20];
    const float* hb1 = (const float*)d_in[21];
    const float* hw2 = (const float*)d_in[22];
    const float* hb2 = (const float*)d_in[23];
    const float* sb = (const float*)d_in[24];
    float* out = (float*)d_out;

    k_pre<<<16, 64, 0, stream>>>(home, anch, pw_w1, pw_b1);
    k_fold<<<57, 256, 0, stream>>>(emb_w, tri_w, ctx_w, ctx_b, emb_b, tri_b);
    k_front_mfma<<<512, 256, 0, stream>>>(emb, tria, rm);
    k_relay<<<1024, 256, 0, stream>>>(pw_w2, pw_b2, pwn_g, pwn_b, gates, norm_g, norm_b,
                                      hw1, hb1, hw2, hb2, sb, out);
}

// Round 6
// 176.390 us; speedup vs baseline: 1.2348x; 1.0634x over previous
//
#include <hip/hip_runtime.h>
#include <hip/hip_bf16.h>
#include <math.h>

#define BTOT 32768

typedef float f32x4 __attribute__((ext_vector_type(4)));
typedef __bf16 v8bf __attribute__((ext_vector_type(8)));

// Scratch in device globals (graph-capture safe).
__device__ float g_x[BTOT * 128];                       // 16.8 MB intermediate
__device__ float g_M[2 * 8 * 16 * 64];                  // folded AT^T @ pw_w1
__device__ float g_b1p[2 * 8 * 64];                     // pw_b1 + colsum(pw_w1)
__device__ __align__(16) unsigned short g_wf[1792 * 128]; // [E;T] bf16, B-fragment-swizzled
__device__ float g_beff[128];                           // ctx_b + emb_b@Wc1 + tri_b@Wc2
__device__ float g_wr[128];                             // ctx_w row 96 (rm column)

__device__ __forceinline__ float gelu_f(float v) {
    return 0.5f * v * (1.0f + erff(v * 0.70710678118654752f));
}

__device__ __forceinline__ unsigned short f2bf_rne(float x) {
    unsigned u = __float_as_uint(x);
    u += 0x7fffu + ((u >> 16) & 1u);
    return (unsigned short)(u >> 16);
}

#define GLOAD16(gp, lp)                                                        \
    __builtin_amdgcn_global_load_lds(                                          \
        (const __attribute__((address_space(1))) void*)(gp),                   \
        (__attribute__((address_space(3))) void*)(lp), 16, 0, 0)

// ---------------------------------------------------------------------------
// k_pre: per (l,p): slerp anchors -> fold AT^T @ pw_w1 into g_M, g_b1p.
// ---------------------------------------------------------------------------
__global__ __launch_bounds__(64) void k_pre(const float* __restrict__ home,
                                            const float* __restrict__ anchors,
                                            const float* __restrict__ pw_w1,
                                            const float* __restrict__ pw_b1) {
    __shared__ float s_AT[48 * 16];
    const int lp = blockIdx.x;   // 0..15  (l*8+p)
    const int tid = threadIdx.x; // 0..63
    if (tid < 48) {
        const int t = tid >> 4, a = tid & 15;
        const float* hp = home + (lp * 16 + a) * 16;
        const float* cp = anchors + (lp * 16 + a) * 16;
        float h[16], c[16], nh = 0.f, nc = 0.f;
#pragma unroll
        for (int i = 0; i < 16; ++i) {
            h[i] = hp[i]; nh = fmaf(h[i], h[i], nh);
            c[i] = cp[i]; nc = fmaf(c[i], c[i], nc);
        }
        const float ih = 1.f / fmaxf(sqrtf(nh), 1e-12f);
        const float ic = 1.f / fmaxf(sqrtf(nc), 1e-12f);
        float cw = 0.f;
#pragma unroll
        for (int i = 0; i < 16; ++i) { h[i] *= ih; c[i] *= ic; cw = fmaf(h[i], c[i], cw); }
        cw = fminf(fmaxf(cw, -1.f + 1e-7f), 1.f - 1e-7f);
        const float om = acosf(cw);
        const float so = fmaxf(sinf(om), 1e-7f);
        const float tt = (float)t * (1.f / 3.f);
        const float s1 = sinf((1.f - tt) * om), s2 = sinf(tt * om);
        float v[16], nv = 0.f;
#pragma unroll
        for (int i = 0; i < 16; ++i) { v[i] = (s1 * h[i] + s2 * c[i]) / so; nv = fmaf(v[i], v[i], nv); }
        const float iv = 1.f / fmaxf(sqrtf(nv), 1e-12f);
#pragma unroll
        for (int i = 0; i < 16; ++i) s_AT[tid * 16 + i] = v[i] * iv;
    }
    __syncthreads();
    const int h = tid;
    const float* w1 = pw_w1 + lp * 48 * 64;
    float b = pw_b1[lp * 64 + h];
    float m[16];
#pragma unroll
    for (int d = 0; d < 16; ++d) m[d] = 0.f;
    for (int j = 0; j < 48; ++j) {
        const float w = w1[j * 64 + h];
        b += w;
#pragma unroll
        for (int d = 0; d < 16; ++d) m[d] = fmaf(s_AT[j * 16 + d], w, m[d]);
    }
    g_b1p[lp * 64 + h] = b;
#pragma unroll
    for (int d = 0; d < 16; ++d) g_M[(lp * 16 + d) * 64 + h] = m[d];
}

// ---------------------------------------------------------------------------
// k_fold: W = [emb_w@Wc1 ; tri_w@Wc2] (1792x128) -> bf16, swizzled into MFMA
// B-fragment-linear order. Block 56 also computes b_eff and wr.
// ---------------------------------------------------------------------------
__global__ __launch_bounds__(256) void k_fold(const float* __restrict__ emb_w,
                                              const float* __restrict__ tri_w,
                                              const float* __restrict__ ctx_w,
                                              const float* __restrict__ ctx_b,
                                              const float* __restrict__ emb_b,
                                              const float* __restrict__ tri_b) {
    if (blockIdx.x == 56) {
        const int n = threadIdx.x;
        if (n < 128) {
            float b = ctx_b[n];
            for (int c = 0; c < 64; ++c) b = fmaf(emb_b[c], ctx_w[c * 128 + n], b);
            for (int c = 0; c < 32; ++c) b = fmaf(tri_b[c], ctx_w[(64 + c) * 128 + n], b);
            g_beff[n] = b;
            g_wr[n] = ctx_w[96 * 128 + n];
        }
        return;
    }
    __shared__ float sctx[97 * 128];
    for (int q = threadIdx.x; q < 3104; q += 256)
        *(float4*)&sctx[q * 4] = *(const float4*)&ctx_w[q * 4];
    __syncthreads();
    const int kt = blockIdx.x;
    const int kr = threadIdx.x >> 3;       // 0..31 row within k-tile
    const int n0 = (threadIdx.x & 7) * 16; // 16 output cols per thread
    const int k = kt * 32 + kr;
    float acc[16];
#pragma unroll
    for (int j = 0; j < 16; ++j) acc[j] = 0.f;
    if (k < 768) {
        const float* wrow = emb_w + k * 64;
        for (int c = 0; c < 64; ++c) {
            const float a = wrow[c];
            const float* cx = &sctx[c * 128 + n0];
#pragma unroll
            for (int j = 0; j < 16; ++j) acc[j] = fmaf(a, cx[j], acc[j]);
        }
    } else {
        const float* wrow = tri_w + (k - 768) * 32;
        for (int c = 0; c < 32; ++c) {
            const float a = wrow[c];
            const float* cx = &sctx[(64 + c) * 128 + n0];
#pragma unroll
            for (int j = 0; j < 16; ++j) acc[j] = fmaf(a, cx[j], acc[j]);
        }
    }
    const int nt = threadIdx.x & 7;
    const int lanehi = (kr >> 3) << 4;
    const int j8 = kr & 7;
#pragma unroll
    for (int q = 0; q < 16; ++q) {
        const int lane = lanehi | q;
        g_wf[((kt * 8 + nt) * 64 + lane) * 8 + j8] = f2bf_rne(acc[q]);
    }
}

// ---------------------------------------------------------------------------
// k_front_mfma (m97-style LDS-staged): unchanged from round 5 (works).
// ---------------------------------------------------------------------------
__global__ __launch_bounds__(256) void k_front_mfma(const float* __restrict__ emb,
                                                    const float* __restrict__ tri,
                                                    const float* __restrict__ rm) {
    __shared__ __align__(16) char lds[65536];   // A0 | A1 | B0 | B1 (16KB each)
    const int tid = threadIdx.x;
    const int lane = tid & 63, w = tid >> 6;
    const int row0 = blockIdx.x * 64;
    const int arow = lane & 15, kgrp = lane >> 4;

    f32x4 acc[8];
#pragma unroll
    for (int nt = 0; nt < 8; ++nt) {
        f32x4 z = {0.f, 0.f, 0.f, 0.f};
        acc[nt] = z;
    }

#define STAGE(kc, buf) {                                                       \
        char* AbBase_ = lds + (buf) * 16384 + w * 4096;        /* uniform */   \
        char* BbBase_ = lds + 32768 + (buf) * 16384 + w * 4096;                \
        const char* gB_ = (const char*)g_wf + (size_t)(kc) * 16384             \
                          + w * 4096 + lane * 16;                              \
        _Pragma("unroll")                                                      \
        for (int i = 0; i < 4; ++i) GLOAD16(gB_ + i * 1024, BbBase_ + i * 1024); \
        _Pragma("unroll")                                                      \
        for (int i = 0; i < 4; ++i) {                                          \
            const int r_ = i * 4 + (lane >> 4);                                \
            const int grow_ = row0 + w * 16 + r_;                              \
            const int colb_ = ((lane & 15) * 16) ^ (r_ << 4);                  \
            const char* gA_ = ((kc) < 12)                                      \
                ? (const char*)(emb + (size_t)grow_ * 768 + (kc) * 64) + colb_ \
                : (const char*)(tri + (size_t)grow_ * 1024 + ((kc) - 12) * 64) + colb_; \
            GLOAD16(gA_, AbBase_ + i * 1024);                                  \
        }                                                                      \
    }

#define COMPUTE(buf) {                                                         \
        const char* Ar_ = lds + (buf) * 16384 + (w * 16 + arow) * 256;         \
        const char* Br_ = lds + 32768 + (buf) * 16384 + lane * 16;             \
        const int msk_ = arow << 4;                                            \
        _Pragma("unroll")                                                      \
        for (int h = 0; h < 2; ++h) {                                          \
            const int c0_ = h * 128 + kgrp * 32;                               \
            const float4 f0_ = *(const float4*)(Ar_ + (c0_ ^ msk_));           \
            const float4 f1_ = *(const float4*)(Ar_ + ((c0_ + 16) ^ msk_));    \
            v8bf a_;                                                           \
            a_[0] = (__bf16)f0_.x; a_[1] = (__bf16)f0_.y;                      \
            a_[2] = (__bf16)f0_.z; a_[3] = (__bf16)f0_.w;                      \
            a_[4] = (__bf16)f1_.x; a_[5] = (__bf16)f1_.y;                      \
            a_[6] = (__bf16)f1_.z; a_[7] = (__bf16)f1_.w;                      \
            const char* bp_ = Br_ + h * 8192;                                  \
            _Pragma("unroll")                                                  \
            for (int nt = 0; nt < 8; ++nt) {                                   \
                const v8bf b_ = *(const v8bf*)(bp_ + nt * 1024);               \
                acc[nt] = __builtin_amdgcn_mfma_f32_16x16x32_bf16(a_, b_, acc[nt], 0, 0, 0); \
            }                                                                  \
        }                                                                      \
    }

    STAGE(0, 0);
    __syncthreads();
    int buf = 0;
    for (int kc = 0; kc < 28; ++kc) {
        if (kc < 27) STAGE(kc + 1, buf ^ 1);
        COMPUTE(buf);
        __syncthreads();
        buf ^= 1;
    }
#undef STAGE
#undef COMPUTE

    const int rowb = row0 + w * 16 + kgrp * 4;
    const f32x4 rv = *(const f32x4*)&rm[rowb];
#pragma unroll
    for (int nt = 0; nt < 8; ++nt) {
        const int col = nt * 16 + arow;
        const float be = g_beff[col];
        const float wv = g_wr[col];
#pragma unroll
        for (int rr = 0; rr < 4; ++rr) {
            g_x[(size_t)(rowb + rr) * 128 + col] = acc[nt][rr] + rv[rr] * wv + be;
        }
    }
}

// ---------------------------------------------------------------------------
// k_relay (R=2 row-paired): thread = (row-pair, patch). Every LDS read of
// M / w2 / b1p / head weights is amortized over 2 rows -> DS wave-ops per row
// halve (the co-bottleneck with VALU at R=1). pn[] eliminated by folding
// inv into the gelu input: h = b1p - inv*(patch@M). 64 rows/block, 512 blocks.
// ---------------------------------------------------------------------------
__global__ __launch_bounds__(256) void k_relay(
    const float* __restrict__ pw_w2, const float* __restrict__ pw_b2,
    const float* __restrict__ pwn_g, const float* __restrict__ pwn_b,
    const float* __restrict__ gates, const float* __restrict__ norm_g,
    const float* __restrict__ norm_b, const float* __restrict__ head_w1,
    const float* __restrict__ head_b1, const float* __restrict__ head_w2,
    const float* __restrict__ head_b2, const float* __restrict__ stats_bias,
    float* __restrict__ out) {
    __shared__ __align__(16) float s_M[8 * 1028];
    __shared__ __align__(16) float s_w2[8 * 1028];
    __shared__ __align__(16) float s_b1p[8 * 68];
    __shared__ __align__(16) float s_hw1[8 * 132];
    __shared__ float s_hb1[64], s_hw2[64], s_hcb[8];
    __shared__ float s_mc[64 * 8];
    const int tid = threadIdx.x;
    const int pr = tid >> 3, p = tid & 7;
    const int rowA = blockIdx.x * 64 + pr * 2;   // rowB = rowA + 1

    {   // stage head weights (256 float4 == 1024 floats exactly)
        const int e = tid * 4, pp = e >> 7, rem = e & 127;
        *(float4*)&s_hw1[pp * 132 + rem] = *(const float4*)&head_w1[e];
    }
    if (tid < 64) { s_hb1[tid] = head_b1[tid]; s_hw2[tid] = head_w2[tid]; }
    if (tid < 8) s_hcb[tid] = head_b2[tid] + stats_bias[tid];

    float xA[16], xB[16];
    {
        const float* xp = g_x + (size_t)rowA * 128 + p * 16;
#pragma unroll
        for (int i = 0; i < 4; ++i) {
            *(float4*)&xA[i * 4] = *(const float4*)&xp[i * 4];
            *(float4*)&xB[i * 4] = *(const float4*)&xp[128 + i * 4];
        }
    }

    for (int l = 0; l < 2; ++l) {
        if (l) __syncthreads();
        for (int q = tid; q < 2048; q += 256) {
            const int e = q * 4, pp = e >> 10, rem = e & 1023;
            *(float4*)&s_M[pp * 1028 + rem] = *(const float4*)&g_M[l * 8192 + e];
            *(float4*)&s_w2[pp * 1028 + rem] = *(const float4*)&pw_w2[l * 8192 + e];
        }
        if (tid < 128) {
            const int e = tid * 4, pp = e >> 6, rem = e & 63;
            *(float4*)&s_b1p[pp * 68 + rem] = *(const float4*)&g_b1p[l * 512 + e];
        }
        __syncthreads();

        // LayerNorm over the 128-dim rows (8 lanes of same pair cooperate)
        float sA = 0.f, qA = 0.f, sB = 0.f, qB = 0.f;
#pragma unroll
        for (int i = 0; i < 16; ++i) {
            sA += xA[i]; qA = fmaf(xA[i], xA[i], qA);
            sB += xB[i]; qB = fmaf(xB[i], xB[i], qB);
        }
#pragma unroll
        for (int m = 1; m < 8; m <<= 1) {
            sA += __shfl_xor(sA, m, 64); qA += __shfl_xor(qA, m, 64);
            sB += __shfl_xor(sB, m, 64); qB += __shfl_xor(qB, m, 64);
        }
        const float muA = sA * (1.f / 128.f);
        const float rsA = rsqrtf(fmaxf(qA * (1.f / 128.f) - muA * muA, 0.f) + 1e-5f);
        const float muB = sB * (1.f / 128.f);
        const float rsB = rsqrtf(fmaxf(qB * (1.f / 128.f) - muB * muB, 0.f) + 1e-5f);
        float paA[16], paB[16], nA = 0.f, nB = 0.f;
#pragma unroll
        for (int i = 0; i < 16; ++i) {
            const float gg = norm_g[l * 128 + p * 16 + i];
            const float bb = norm_b[l * 128 + p * 16 + i];
            const float vA = (xA[i] - muA) * rsA * gg + bb;
            const float vB = (xB[i] - muB) * rsB * gg + bb;
            paA[i] = vA; nA = fmaf(vA, vA, nA);
            paB[i] = vB; nB = fmaf(vB, vB, nB);
        }
        const float invA = 1.f / fmaxf(sqrtf(nA), 1e-12f);
        const float invB = 1.f / fmaxf(sqrtf(nB), 1e-12f);

        float pwA[16], pwB[16];
#pragma unroll
        for (int i = 0; i < 16; ++i) {
            const float b2 = pw_b2[(l * 8 + p) * 16 + i];
            pwA[i] = b2; pwB[i] = b2;
        }
        const float* Mp = &s_M[p * 1028];
        const float* W2p = &s_w2[p * 1028];
        const float* Bp = &s_b1p[p * 68];
        for (int h4 = 0; h4 < 16; ++h4) {
            float bq[4];
            *(float4*)bq = *(const float4*)&Bp[h4 * 4];
            float aA[4] = {0.f, 0.f, 0.f, 0.f};
            float aB[4] = {0.f, 0.f, 0.f, 0.f};
#pragma unroll
            for (int d = 0; d < 16; ++d) {
                float m4[4];
                *(float4*)m4 = *(const float4*)&Mp[d * 64 + h4 * 4];
#pragma unroll
                for (int j = 0; j < 4; ++j) {
                    aA[j] = fmaf(paA[d], m4[j], aA[j]);
                    aB[j] = fmaf(paB[d], m4[j], aB[j]);
                }
            }
#pragma unroll
            for (int j = 0; j < 4; ++j) {
                const float gA = gelu_f(bq[j] - invA * aA[j]);
                const float gB = gelu_f(bq[j] - invB * aB[j]);
                float w[16];
#pragma unroll
                for (int u = 0; u < 4; ++u)
                    *(float4*)&w[u * 4] = *(const float4*)&W2p[(h4 * 4 + j) * 16 + u * 4];
#pragma unroll
                for (int u = 0; u < 16; ++u) {
                    pwA[u] = fmaf(gA, w[u], pwA[u]);
                    pwB[u] = fmaf(gB, w[u], pwB[u]);
                }
            }
        }
        // LN16 on pw, gate, residual combine (both rows)
        float s2A = 0.f, q2A = 0.f, s2B = 0.f, q2B = 0.f;
#pragma unroll
        for (int i = 0; i < 16; ++i) {
            s2A += pwA[i]; q2A = fmaf(pwA[i], pwA[i], q2A);
            s2B += pwB[i]; q2B = fmaf(pwB[i], pwB[i], q2B);
        }
        const float mu2A = s2A * (1.f / 16.f);
        const float rs2A = rsqrtf(fmaxf(q2A * (1.f / 16.f) - mu2A * mu2A, 0.f) + 1e-5f);
        const float mu2B = s2B * (1.f / 16.f);
        const float rs2B = rsqrtf(fmaxf(q2B * (1.f / 16.f) - mu2B * mu2B, 0.f) + 1e-5f);
        const float gate = 1.f / (1.f + expf(-gates[l * 8 + p]));
#pragma unroll
        for (int i = 0; i < 16; ++i) {
            const float pg = pwn_g[l * 16 + i], pb = pwn_b[l * 16 + i];
            const float vA = (pwA[i] - mu2A) * rs2A * pg + pb;
            const float vB = (pwB[i] - mu2B) * rs2B * pg + pb;
            xA[i] = xA[i] + gate * vA + (1.f - gate) * paA[i];
            xB[i] = xB[i] + gate * vB + (1.f - gate) * paB[i];
        }
    }

    // head: per (row-pair, patch), head weights amortized over both rows
    float accmA = s_hcb[p], accmB = accmA;
#pragma unroll
    for (int j = 0; j < 8; ++j) {
        float aA = s_hb1[p * 8 + j], aB = aA;
#pragma unroll
        for (int d = 0; d < 16; ++d) {
            const float w = s_hw1[p * 132 + d * 8 + j];
            aA = fmaf(xA[d], w, aA);
            aB = fmaf(xB[d], w, aB);
        }
        const float w2h = s_hw2[p * 8 + j];
        accmA = fmaf(gelu_f(aA), w2h, accmA);
        accmB = fmaf(gelu_f(aB), w2h, accmB);
    }
    const float mcA = 0.1f + 4.9f / (1.f + expf(-accmA));
    const float mcB = 0.1f + 4.9f / (1.f + expf(-accmB));
    s_mc[(pr * 2) * 8 + p] = mcA;
    s_mc[(pr * 2 + 1) * 8 + p] = mcB;
    out[(size_t)33554432 + (size_t)rowA * 8 + p] = mcA;
    out[(size_t)33554432 + (size_t)(rowA + 1) * 8 + p] = mcB;
    __syncthreads();

    // mag = repeat(mc, 128): cooperative fully-coalesced float4 writes
    const size_t base = (size_t)blockIdx.x * 64 * 1024;
#pragma unroll
    for (int it = 0; it < 64; ++it) {
        const int idx = it * 256 + tid;
        const int rr = idx >> 8, c4 = idx & 255;
        const float v = s_mc[rr * 8 + (c4 >> 5)];
        const float4 vv = make_float4(v, v, v, v);
        *(float4*)&out[base + rr * 1024 + c4 * 4] = vv;
    }
}

// ---------------------------------------------------------------------------
extern "C" void kernel_launch(void* const* d_in, const int* in_sizes, int n_in,
                              void* d_out, int out_size, void* d_ws, size_t ws_size,
                              hipStream_t stream) {
    (void)in_sizes; (void)n_in; (void)d_ws; (void)ws_size; (void)out_size;
    const float* emb = (const float*)d_in[0];
    const float* tria = (const float*)d_in[1];
    const float* rm = (const float*)d_in[2];
    const float* emb_w = (const float*)d_in[3];
    const float* emb_b = (const float*)d_in[4];
    const float* tri_w = (const float*)d_in[5];
    const float* tri_b = (const float*)d_in[6];
    const float* ctx_w = (const float*)d_in[7];
    const float* ctx_b = (const float*)d_in[8];
    const float* home = (const float*)d_in[9];
    const float* anch = (const float*)d_in[10];
    const float* pw_w1 = (const float*)d_in[11];
    const float* pw_b1 = (const float*)d_in[12];
    const float* pw_w2 = (const float*)d_in[13];
    const float* pw_b2 = (const float*)d_in[14];
    const float* pwn_g = (const float*)d_in[15];
    const float* pwn_b = (const float*)d_in[16];
    const float* gates = (const float*)d_in[17];
    const float* norm_g = (const float*)d_in[18];
    const float* norm_b = (const float*)d_in[19];
    const float* hw1 = (const float*)d_in[20];
    const float* hb1 = (const float*)d_in[21];
    const float* hw2 = (const float*)d_in[22];
    const float* hb2 = (const float*)d_in[23];
    const float* sb = (const float*)d_in[24];
    float* out = (float*)d_out;

    k_pre<<<16, 64, 0, stream>>>(home, anch, pw_w1, pw_b1);
    k_fold<<<57, 256, 0, stream>>>(emb_w, tri_w, ctx_w, ctx_b, emb_b, tri_b);
    k_front_mfma<<<512, 256, 0, stream>>>(emb, tria, rm);
    k_relay<<<512, 256, 0, stream>>>(pw_w2, pw_b2, pwn_g, pwn_b, gates, norm_g, norm_b,
                                     hw1, hb1, hw2, hb2, sb, out);
}